// Round 5
// baseline (1078.938 us; speedup 1.0000x reference)
//
#include <hip/hip_runtime.h>
#include <hip/hip_bf16.h>
#include <hip/hip_fp8.h>
#include <cstdint>
#include <cstddef>

// Problem constants
#define NN     20000     // nodes
#define NF     128       // in features
#define NH     56        // heads
#define OC     32        // out channels per head
#define DD1    1792      // NH*OC
#define NE     100000    // edges (before self loops)
#define ETOT   120000    // edges + self loops
#define NG     50        // graphs
#define EPS_BN 1e-5f

typedef __bf16 bf16x8 __attribute__((ext_vector_type(8)));
typedef float  floatx4 __attribute__((ext_vector_type(4)));
typedef unsigned int u32;
typedef __attribute__((address_space(1))) u32 gu32;
typedef __attribute__((address_space(3))) u32 lu32;

__device__ __forceinline__ void async_copy16(void* lds, const void* g) {
    __builtin_amdgcn_global_load_lds((gu32*)const_cast<void*>(g), (lu32*)lds, 16, 0, 0);
}

// decode 4 fp8 (e4m3, packed in u32) and accumulate a*val into acc[0..3]
__device__ __forceinline__ void fma_fp8x4(u32 u, float a, float* acc) {
    #pragma unroll
    for (int b = 0; b < 4; ++b) {
        __hip_fp8_e4m3 t;
        t.__x = (u >> (8 * b)) & 0xff;
        acc[b] += a * (float)t;
    }
}

// ---------------- elementwise cast fp32 -> bf16 ----------------
__global__ __launch_bounds__(256) void cast_bf16_kernel(const float* __restrict__ in,
                                                        __hip_bfloat16* __restrict__ out, int n) {
    int i = blockIdx.x * 256 + threadIdx.x;
    if (i < n) out[i] = __float2bfloat16(in[i]);
}

// ---------------- tiled transpose + cast: in[R][C] f32 -> out[C][R] bf16 ----------------
__global__ __launch_bounds__(256) void transpose_cast_kernel(const float* __restrict__ in,
                                                             __hip_bfloat16* __restrict__ out,
                                                             int R, int C) {
    __shared__ float tile[32][33];
    int c0 = blockIdx.x * 32, r0 = blockIdx.y * 32;
    int tx = threadIdx.x & 31, ty = threadIdx.x >> 5;   // ty in 0..7
    #pragma unroll
    for (int i = 0; i < 32; i += 8) {
        int r = r0 + ty + i, c = c0 + tx;
        if (r < R && c < C) tile[ty + i][tx] = in[(size_t)r * C + c];
    }
    __syncthreads();
    #pragma unroll
    for (int i = 0; i < 32; i += 8) {
        int c = c0 + ty + i, r = r0 + tx;
        if (c < C && r < R) out[(size_t)c * R + r] = __float2bfloat16(tile[tx][ty + i]);
    }
}

// ---------------- CSR build: histogram / scan / scatter ----------------
__global__ __launch_bounds__(256) void hist_kernel(const int* __restrict__ ei, int* __restrict__ deg) {
    int i = blockIdx.x * 256 + threadIdx.x;
    if (i >= ETOT) return;
    int dst = (i < NE) ? ei[NE + i] : (i - NE);
    atomicAdd(&deg[dst], 1);
}

__global__ __launch_bounds__(1024) void scan_kernel(const int* __restrict__ deg,
                                                    int* __restrict__ rowptr,
                                                    int* __restrict__ cursor) {
    __shared__ int buf[1024];
    int t = threadIdx.x;
    const int CH = (NN + 1023) >> 10;   // 20
    int base = t * CH;
    int s = 0;
    for (int j = 0; j < CH; ++j) { int idx = base + j; if (idx < NN) s += deg[idx]; }
    buf[t] = s;
    __syncthreads();
    for (int off = 1; off < 1024; off <<= 1) {
        int v = (t >= off) ? buf[t - off] : 0;
        __syncthreads();
        buf[t] += v;
        __syncthreads();
    }
    int run = buf[t] - s;   // exclusive
    for (int j = 0; j < CH; ++j) {
        int idx = base + j;
        if (idx < NN) { rowptr[idx] = run; cursor[idx] = run; run += deg[idx]; }
    }
    if (t == 1023) rowptr[NN] = buf[1023];
}

__global__ __launch_bounds__(256) void scatter_kernel(const int* __restrict__ ei,
                                                      int* __restrict__ cursor,
                                                      int* __restrict__ csr_src) {
    int i = blockIdx.x * 256 + threadIdx.x;
    if (i >= ETOT) return;
    int s, d;
    if (i < NE) { s = ei[i]; d = ei[NE + i]; } else { s = i - NE; d = i - NE; }
    int pos = atomicAdd(&cursor[d], 1);
    csr_src[pos] = s;
}

// ---------------- bf16 MFMA GEMM: C = A * Bt^T, writes bf16 C AND fp8 C8 ----------------
__global__ __launch_bounds__(256) void gemm_bf16(const __hip_bfloat16* __restrict__ A,
                                                 const __hip_bfloat16* __restrict__ Bt,
                                                 __hip_bfloat16* __restrict__ C,
                                                 unsigned char* __restrict__ C8,
                                                 int M, int N, int K) {
    __shared__ __align__(16) unsigned short lsA[128 * 32];
    __shared__ __align__(16) unsigned short lsB[128 * 32];
    const int tid  = threadIdx.x;
    const int lane = tid & 63, wave = tid >> 6;
    const int wm = wave >> 1, wn = wave & 1;
    const int m0 = blockIdx.y * 128, n0 = blockIdx.x * 128;

    floatx4 zero = {0.f, 0.f, 0.f, 0.f};
    floatx4 acc[4][4];
    #pragma unroll
    for (int i = 0; i < 4; ++i)
        #pragma unroll
        for (int j = 0; j < 4; ++j) acc[i][j] = zero;

    for (int k0 = 0; k0 < K; k0 += 32) {
        #pragma unroll
        for (int i = 0; i < 2; ++i) {
            int slot = tid + i * 256;
            int row = slot >> 2, seg = slot & 3;
            int gseg = seg ^ ((row >> 1) & 3);
            int gr = m0 + row; if (gr > M - 1) gr = M - 1;
            async_copy16(&lsA[slot * 8], A + (size_t)gr * K + k0 + gseg * 8);
        }
        #pragma unroll
        for (int i = 0; i < 2; ++i) {
            int slot = tid + i * 256;
            int row = slot >> 2, seg = slot & 3;
            int gseg = seg ^ ((row >> 1) & 3);
            async_copy16(&lsB[slot * 8], Bt + (size_t)(n0 + row) * K + k0 + gseg * 8);
        }
        __syncthreads();

        bf16x8 aF[4], bF[4];
        const int q = lane >> 4;
        #pragma unroll
        for (int mt = 0; mt < 4; ++mt) {
            int row = wm * 64 + mt * 16 + (lane & 15);
            int seg = q ^ ((row >> 1) & 3);
            aF[mt] = *(const bf16x8*)&lsA[row * 32 + seg * 8];
        }
        #pragma unroll
        for (int nt = 0; nt < 4; ++nt) {
            int row = wn * 64 + nt * 16 + (lane & 15);
            int seg = q ^ ((row >> 1) & 3);
            bF[nt] = *(const bf16x8*)&lsB[row * 32 + seg * 8];
        }
        #pragma unroll
        for (int mt = 0; mt < 4; ++mt)
            #pragma unroll
            for (int nt = 0; nt < 4; ++nt)
                acc[mt][nt] = __builtin_amdgcn_mfma_f32_16x16x32_bf16(aF[mt], bF[nt], acc[mt][nt], 0, 0, 0);
        __syncthreads();
    }

    #pragma unroll
    for (int mt = 0; mt < 4; ++mt) {
        #pragma unroll
        for (int r = 0; r < 4; ++r) {
            int rowc = m0 + wm * 64 + mt * 16 + (lane >> 4) * 4 + r;
            if (rowc < M) {
                #pragma unroll
                for (int nt = 0; nt < 4; ++nt) {
                    int col = n0 + wn * 64 + nt * 16 + (lane & 15);
                    float v = acc[mt][nt][r];
                    C[(size_t)rowc * N + col] = __float2bfloat16(v);
                    __hip_fp8_e4m3 q8(v);
                    C8[(size_t)rowc * N + col] = q8.__x;
                }
            }
        }
    }
}

// ---------------- attention scores: as/ad[n,h] = sum_o h[n,h,o]*att[h,o] ----------------
__global__ __launch_bounds__(256) void attn_score(const __hip_bfloat16* __restrict__ h,
                                                  const float* __restrict__ att_src,
                                                  const float* __restrict__ att_dst,
                                                  float* __restrict__ as_,
                                                  float* __restrict__ ad_) {
    int wave = threadIdx.x >> 6, lane = threadIdx.x & 63;
    int node = blockIdx.x * 4 + wave;
    if (node >= NN || lane >= NH) return;
    const bf16x8* hp = (const bf16x8*)(h + (size_t)node * DD1 + lane * OC);
    float s = 0.f, d = 0.f;
    #pragma unroll
    for (int jj = 0; jj < 4; ++jj) {
        bf16x8 hv = hp[jj];
        #pragma unroll
        for (int j = 0; j < 8; ++j) {
            float v = (float)hv[j];
            int o = jj * 8 + j;
            s += v * att_src[lane * OC + o];
            d += v * att_dst[lane * OC + o];
        }
    }
    as_[node * NH + lane] = s;
    ad_[node * NH + lane] = d;
}

// ---------------- fused per-dst score + softmax -> bf16 alpha ----------------
// one wave per dst node, lane = head. as-gather footprint 4.5 MB (L2-resident).
__global__ __launch_bounds__(256) void score_softmax(const int* __restrict__ rowptr,
                                                     const int* __restrict__ csr_src,
                                                     const float* __restrict__ as_,
                                                     const float* __restrict__ ad_,
                                                     __hip_bfloat16* __restrict__ alpha) {
    int wave = threadIdx.x >> 6, lane = threadIdx.x & 63;
    int node = blockIdx.x * 4 + wave;
    if (node >= NN || lane >= NH) return;
    int e0 = rowptr[node], e1 = rowptr[node + 1];
    float adv = ad_[(size_t)node * NH + lane];

    float m = -1e30f;
    for (int e = e0; e < e1; ++e) {
        int s = csr_src[e];
        float v = as_[(size_t)s * NH + lane] + adv;
        v = v > 0.f ? v : 0.2f * v;
        m = fmaxf(m, v);
    }
    float den = 0.f;
    for (int e = e0; e < e1; ++e) {
        int s = csr_src[e];
        float v = as_[(size_t)s * NH + lane] + adv;
        v = v > 0.f ? v : 0.2f * v;
        den += __expf(v - m);
    }
    float inv = 1.f / den;
    for (int e = e0; e < e1; ++e) {
        int s = csr_src[e];
        float v = as_[(size_t)s * NH + lane] + adv;
        v = v > 0.f ? v : 0.2f * v;
        alpha[(size_t)e * NH + lane] = __float2bfloat16(__expf(v - m) * inv);
    }
}

// ---------------- per-dst aggregation: wave/node, fp8 h gather ----------------
// lane covers 16 features at 16*lane (pass 0) and 1024+16*lane (pass 1, lane<48).
// LAYER==1: out = bf16 h1p[n][1792] = BN1(ELU(agg + b1))
// LAYER==2: out = f32  h2s[n][32]   = BN2(mean_heads(agg) + b2)
template <int LAYER>
__global__ __launch_bounds__(256) void attn_aggregate(const int* __restrict__ rowptr,
                                                      const int* __restrict__ csr_src,
                                                      const __hip_bfloat16* __restrict__ alpha,
                                                      const unsigned char* __restrict__ h8,
                                                      const float* __restrict__ bias,
                                                      const float* __restrict__ bng,
                                                      const float* __restrict__ bnb,
                                                      const float* __restrict__ bnm,
                                                      const float* __restrict__ bnv,
                                                      void* __restrict__ outp) {
    __shared__ int srcl[4][64];
    const int wv = threadIdx.x >> 6, lane = threadIdx.x & 63;
    const int n = blockIdx.x * 4 + wv;              // NN divisible by 4
    const int e0 = rowptr[n], e1 = rowptr[n + 1];
    const int head0 = lane >> 1;                    // head of pass-0 slice
    const bool p1 = (lane < 48);

    float acc[2][16];
    #pragma unroll
    for (int p = 0; p < 2; ++p)
        #pragma unroll
        for (int k = 0; k < 16; ++k) acc[p][k] = 0.f;

    for (int base = e0; base < e1; base += 64) {
        int cnt = min(64, e1 - base);
        if (lane < cnt) srcl[wv][lane] = csr_src[base + lane];
        for (int i = 0; i < cnt; ++i) {
            int s = srcl[wv][i];
            const uint4* row = (const uint4*)(h8 + (size_t)s * DD1);
            const __hip_bfloat16* arow = alpha + (size_t)(base + i) * NH;
            uint4 q0 = row[lane];
            uint4 q1 = p1 ? row[64 + lane] : make_uint4(0, 0, 0, 0);
            float a0 = (float)arow[head0];
            float a1 = p1 ? (float)arow[32 + head0] : 0.f;
            fma_fp8x4(q0.x, a0, &acc[0][0]);
            fma_fp8x4(q0.y, a0, &acc[0][4]);
            fma_fp8x4(q0.z, a0, &acc[0][8]);
            fma_fp8x4(q0.w, a0, &acc[0][12]);
            if (p1) {
                fma_fp8x4(q1.x, a1, &acc[1][0]);
                fma_fp8x4(q1.y, a1, &acc[1][4]);
                fma_fp8x4(q1.z, a1, &acc[1][8]);
                fma_fp8x4(q1.w, a1, &acc[1][12]);
            }
        }
    }

    if constexpr (LAYER == 1) {
        __hip_bfloat16* op = (__hip_bfloat16*)outp + (size_t)n * DD1;
        #pragma unroll
        for (int p = 0; p < 2; ++p) {
            if (p == 1 && !p1) break;
            int c0 = p * 1024 + 16 * lane;
            #pragma unroll
            for (int k = 0; k < 16; ++k) {
                int d = c0 + k;
                float v = acc[p][k] + bias[d];
                v = v > 0.f ? v : expm1f(v);                                  // ELU
                v = (v - bnm[d]) * rsqrtf(bnv[d] + EPS_BN) * bng[d] + bnb[d]; // BN1
                op[d] = __float2bfloat16(v);
            }
        }
    } else {
        __shared__ float fin[4][DD1];   // per-wave staging for head-mean
        #pragma unroll
        for (int p = 0; p < 2; ++p) {
            if (p == 1 && !p1) break;
            int c0 = p * 1024 + 16 * lane;
            #pragma unroll
            for (int k = 0; k < 16; ++k) fin[wv][c0 + k] = acc[p][k];
        }
        // same-wave LDS ordering via lgkmcnt
        if (lane < OC) {
            float s = 0.f;
            #pragma unroll
            for (int hh = 0; hh < NH; ++hh) s += fin[wv][hh * OC + lane];
            float v = s * (1.f / NH) + bias[lane];
            v = (v - bnm[lane]) * rsqrtf(bnv[lane] + EPS_BN) * bng[lane] + bnb[lane]; // BN2
            ((float*)outp)[(size_t)n * OC + lane] = v;
        }
    }
}

// ---------------- mean pool (atomics) + final linear ----------------
__global__ __launch_bounds__(256) void pool_kernel(const float* __restrict__ h2s,
                                                   const int* __restrict__ batch,
                                                   float* __restrict__ sums,
                                                   float* __restrict__ cnt) {
    int gid = blockIdx.x * 256 + threadIdx.x;
    if (gid >= NN * OC) return;
    int node = gid >> 5, ch = gid & 31;
    int g = batch[node];
    atomicAdd(&sums[g * OC + ch], h2s[gid]);
    if (ch == 0) atomicAdd(&cnt[g], 1.0f);
}

__global__ __launch_bounds__(128) void final_kernel(const float* __restrict__ sums,
                                                    const float* __restrict__ cnt,
                                                    const float* __restrict__ lin_w,
                                                    const float* __restrict__ lin_b,
                                                    float* __restrict__ out) {
    int t = threadIdx.x;
    if (t >= NG * 2) return;
    int g = t >> 1, c = t & 1;
    float invc = 1.f / fmaxf(cnt[g], 1.f);
    float acc = lin_b[c];
    #pragma unroll
    for (int o = 0; o < OC; ++o) acc += sums[g * OC + o] * invc * lin_w[o * 2 + c];
    out[t] = acc;
}

// ---------------- host-side launch ----------------
extern "C" void kernel_launch(void* const* d_in, const int* in_sizes, int n_in,
                              void* d_out, int out_size, void* d_ws, size_t ws_size,
                              hipStream_t stream) {
    const float* x    = (const float*)d_in[0];
    const int*   ei   = (const int*)d_in[1];
    const int*   bat  = (const int*)d_in[2];
    const float* W1   = (const float*)d_in[3];
    const float* at_s1 = (const float*)d_in[4];
    const float* at_d1 = (const float*)d_in[5];
    const float* b1   = (const float*)d_in[6];
    const float* bn1g = (const float*)d_in[7];
    const float* bn1b = (const float*)d_in[8];
    const float* bn1m = (const float*)d_in[9];
    const float* bn1v = (const float*)d_in[10];
    const float* W2   = (const float*)d_in[11];
    const float* at_s2 = (const float*)d_in[12];
    const float* at_d2 = (const float*)d_in[13];
    const float* b2   = (const float*)d_in[14];
    const float* bn2g = (const float*)d_in[15];
    const float* bn2b = (const float*)d_in[16];
    const float* bn2m = (const float*)d_in[17];
    const float* bn2v = (const float*)d_in[18];
    const float* linw = (const float*)d_in[19];
    const float* linb = (const float*)d_in[20];
    float* out = (float*)d_out;

    char* wsp = (char*)d_ws;
    auto alloc = [&](size_t bytes) -> void* {
        void* p = (void*)wsp;
        wsp += (bytes + 255) & ~(size_t)255;
        return p;
    };
    __hip_bfloat16* h1  = (__hip_bfloat16*)alloc((size_t)NN * DD1 * 2);  // reused as h2
    unsigned char*  h8  = (unsigned char*)alloc((size_t)NN * DD1);      // fp8 copy, reused as h2f8
    __hip_bfloat16* h1p = (__hip_bfloat16*)alloc((size_t)NN * DD1 * 2);
    __hip_bfloat16* xb  = (__hip_bfloat16*)alloc((size_t)NN * NF * 2);
    __hip_bfloat16* w1t = (__hip_bfloat16*)alloc((size_t)DD1 * NF * 2);
    __hip_bfloat16* w2t = (__hip_bfloat16*)alloc((size_t)DD1 * DD1 * 2);
    float* asb   = (float*)alloc((size_t)NN * NH * 4);
    float* adb   = (float*)alloc((size_t)NN * NH * 4);
    int*   deg   = (int*)alloc((size_t)NN * 4);
    int*   rowp  = (int*)alloc((size_t)(NN + 1) * 4);
    int*   curs  = (int*)alloc((size_t)NN * 4);
    int*   csr   = (int*)alloc((size_t)ETOT * 4);
    __hip_bfloat16* alp = (__hip_bfloat16*)alloc((size_t)ETOT * NH * 2);
    float* h2s   = (float*)alloc((size_t)NN * OC * 4);
    float* sums  = (float*)alloc((size_t)(NG * OC + NG) * 4);
    float* cnt   = sums + NG * OC;

    hipMemsetAsync(deg, 0, (size_t)NN * 4, stream);
    hipMemsetAsync(sums, 0, (size_t)(NG * OC + NG) * 4, stream);

    cast_bf16_kernel<<<(NN * NF + 255) / 256, 256, 0, stream>>>(x, xb, NN * NF);
    transpose_cast_kernel<<<dim3(DD1 / 32, NF / 32), 256, 0, stream>>>(W1, w1t, NF, DD1);
    transpose_cast_kernel<<<dim3(DD1 / 32, DD1 / 32), 256, 0, stream>>>(W2, w2t, DD1, DD1);
    hist_kernel<<<(ETOT + 255) / 256, 256, 0, stream>>>(ei, deg);
    scan_kernel<<<1, 1024, 0, stream>>>(deg, rowp, curs);
    scatter_kernel<<<(ETOT + 255) / 256, 256, 0, stream>>>(ei, curs, csr);

    // layer 1
    gemm_bf16<<<dim3(DD1 / 128, (NN + 127) / 128), 256, 0, stream>>>(xb, w1t, h1, h8, NN, DD1, NF);
    attn_score<<<NN / 4, 256, 0, stream>>>(h1, at_s1, at_d1, asb, adb);
    score_softmax<<<NN / 4, 256, 0, stream>>>(rowp, csr, asb, adb, alp);
    attn_aggregate<1><<<NN / 4, 256, 0, stream>>>(rowp, csr, alp, h8, b1, bn1g, bn1b, bn1m, bn1v, (void*)h1p);

    // layer 2
    gemm_bf16<<<dim3(DD1 / 128, (NN + 127) / 128), 256, 0, stream>>>(h1p, w2t, h1, h8, NN, DD1, DD1);
    attn_score<<<NN / 4, 256, 0, stream>>>(h1, at_s2, at_d2, asb, adb);
    score_softmax<<<NN / 4, 256, 0, stream>>>(rowp, csr, asb, adb, alp);
    attn_aggregate<2><<<NN / 4, 256, 0, stream>>>(rowp, csr, alp, h8, b2, bn2g, bn2b, bn2m, bn2v, (void*)h2s);

    pool_kernel<<<(NN * OC) / 256, 256, 0, stream>>>(h2s, bat, sums, cnt);
    final_kernel<<<1, 128, 0, stream>>>(sums, cnt, linw, linb, out);
}

// Round 6
// 836.097 us; speedup vs baseline: 1.2904x; 1.2904x over previous
//
#include <hip/hip_runtime.h>
#include <hip/hip_bf16.h>
#include <hip/hip_fp8.h>
#include <cstdint>
#include <cstddef>

// Problem constants
#define NN     20000     // nodes
#define NF     128       // in features
#define NH     56        // heads
#define OC     32        // out channels per head
#define DD1    1792     // NH*OC
#define NE     100000    // edges (before self loops)
#define ETOT   120000    // edges + self loops
#define NG     50        // graphs
#define EPS_BN 1e-5f
#define GRP    16        // nodes per wave in aggregate
#define EB     8         // edge batch (loads in flight)

typedef __bf16 bf16x8 __attribute__((ext_vector_type(8)));
typedef float  floatx4 __attribute__((ext_vector_type(4)));
typedef unsigned int u32;
typedef __attribute__((address_space(1))) u32 gu32;
typedef __attribute__((address_space(3))) u32 lu32;

__device__ __forceinline__ void async_copy16(void* lds, const void* g) {
    __builtin_amdgcn_global_load_lds((gu32*)const_cast<void*>(g), (lu32*)lds, 16, 0, 0);
}

// decode 4 fp8 (e4m3, packed in u32) and accumulate a*val into acc[0..3]
__device__ __forceinline__ void fma_fp8x4(u32 u, float a, float* acc) {
    #pragma unroll
    for (int b = 0; b < 4; ++b) {
        __hip_fp8_e4m3 t;
        t.__x = (u >> (8 * b)) & 0xff;
        acc[b] += a * (float)t;
    }
}

// ---------------- elementwise cast fp32 -> bf16 ----------------
__global__ __launch_bounds__(256) void cast_bf16_kernel(const float* __restrict__ in,
                                                        __hip_bfloat16* __restrict__ out, int n) {
    int i = blockIdx.x * 256 + threadIdx.x;
    if (i < n) out[i] = __float2bfloat16(in[i]);
}

// ---------------- tiled transpose + cast: in[R][C] f32 -> out[C][R] bf16 ----------------
__global__ __launch_bounds__(256) void transpose_cast_kernel(const float* __restrict__ in,
                                                             __hip_bfloat16* __restrict__ out,
                                                             int R, int C) {
    __shared__ float tile[32][33];
    int c0 = blockIdx.x * 32, r0 = blockIdx.y * 32;
    int tx = threadIdx.x & 31, ty = threadIdx.x >> 5;   // ty in 0..7
    #pragma unroll
    for (int i = 0; i < 32; i += 8) {
        int r = r0 + ty + i, c = c0 + tx;
        if (r < R && c < C) tile[ty + i][tx] = in[(size_t)r * C + c];
    }
    __syncthreads();
    #pragma unroll
    for (int i = 0; i < 32; i += 8) {
        int c = c0 + ty + i, r = r0 + tx;
        if (c < C && r < R) out[(size_t)c * R + r] = __float2bfloat16(tile[tx][ty + i]);
    }
}

// ---------------- CSR build: histogram / scan / scatter ----------------
__global__ __launch_bounds__(256) void hist_kernel(const int* __restrict__ ei, int* __restrict__ deg) {
    int i = blockIdx.x * 256 + threadIdx.x;
    if (i >= ETOT) return;
    int dst = (i < NE) ? ei[NE + i] : (i - NE);
    atomicAdd(&deg[dst], 1);
}

__global__ __launch_bounds__(1024) void scan_kernel(const int* __restrict__ deg,
                                                    int* __restrict__ rowptr,
                                                    int* __restrict__ cursor) {
    __shared__ int buf[1024];
    int t = threadIdx.x;
    const int CH = (NN + 1023) >> 10;   // 20
    int base = t * CH;
    int s = 0;
    for (int j = 0; j < CH; ++j) { int idx = base + j; if (idx < NN) s += deg[idx]; }
    buf[t] = s;
    __syncthreads();
    for (int off = 1; off < 1024; off <<= 1) {
        int v = (t >= off) ? buf[t - off] : 0;
        __syncthreads();
        buf[t] += v;
        __syncthreads();
    }
    int run = buf[t] - s;   // exclusive
    for (int j = 0; j < CH; ++j) {
        int idx = base + j;
        if (idx < NN) { rowptr[idx] = run; cursor[idx] = run; run += deg[idx]; }
    }
    if (t == 1023) rowptr[NN] = buf[1023];
}

__global__ __launch_bounds__(256) void scatter_kernel(const int* __restrict__ ei,
                                                      int* __restrict__ cursor,
                                                      int* __restrict__ csr_src) {
    int i = blockIdx.x * 256 + threadIdx.x;
    if (i >= ETOT) return;
    int s, d;
    if (i < NE) { s = ei[i]; d = ei[NE + i]; } else { s = i - NE; d = i - NE; }
    int pos = atomicAdd(&cursor[d], 1);
    csr_src[pos] = s;
}

// ---------------- bf16 MFMA GEMM: C = A * Bt^T, writes bf16 C AND fp8 C8 ----------------
__global__ __launch_bounds__(256) void gemm_bf16(const __hip_bfloat16* __restrict__ A,
                                                 const __hip_bfloat16* __restrict__ Bt,
                                                 __hip_bfloat16* __restrict__ C,
                                                 unsigned char* __restrict__ C8,
                                                 int M, int N, int K) {
    __shared__ __align__(16) unsigned short lsA[128 * 32];
    __shared__ __align__(16) unsigned short lsB[128 * 32];
    const int tid  = threadIdx.x;
    const int lane = tid & 63, wave = tid >> 6;
    const int wm = wave >> 1, wn = wave & 1;
    const int m0 = blockIdx.y * 128, n0 = blockIdx.x * 128;

    floatx4 zero = {0.f, 0.f, 0.f, 0.f};
    floatx4 acc[4][4];
    #pragma unroll
    for (int i = 0; i < 4; ++i)
        #pragma unroll
        for (int j = 0; j < 4; ++j) acc[i][j] = zero;

    for (int k0 = 0; k0 < K; k0 += 32) {
        #pragma unroll
        for (int i = 0; i < 2; ++i) {
            int slot = tid + i * 256;
            int row = slot >> 2, seg = slot & 3;
            int gseg = seg ^ ((row >> 1) & 3);
            int gr = m0 + row; if (gr > M - 1) gr = M - 1;
            async_copy16(&lsA[slot * 8], A + (size_t)gr * K + k0 + gseg * 8);
        }
        #pragma unroll
        for (int i = 0; i < 2; ++i) {
            int slot = tid + i * 256;
            int row = slot >> 2, seg = slot & 3;
            int gseg = seg ^ ((row >> 1) & 3);
            async_copy16(&lsB[slot * 8], Bt + (size_t)(n0 + row) * K + k0 + gseg * 8);
        }
        __syncthreads();

        bf16x8 aF[4], bF[4];
        const int q = lane >> 4;
        #pragma unroll
        for (int mt = 0; mt < 4; ++mt) {
            int row = wm * 64 + mt * 16 + (lane & 15);
            int seg = q ^ ((row >> 1) & 3);
            aF[mt] = *(const bf16x8*)&lsA[row * 32 + seg * 8];
        }
        #pragma unroll
        for (int nt = 0; nt < 4; ++nt) {
            int row = wn * 64 + nt * 16 + (lane & 15);
            int seg = q ^ ((row >> 1) & 3);
            bF[nt] = *(const bf16x8*)&lsB[row * 32 + seg * 8];
        }
        #pragma unroll
        for (int mt = 0; mt < 4; ++mt)
            #pragma unroll
            for (int nt = 0; nt < 4; ++nt)
                acc[mt][nt] = __builtin_amdgcn_mfma_f32_16x16x32_bf16(aF[mt], bF[nt], acc[mt][nt], 0, 0, 0);
        __syncthreads();
    }

    #pragma unroll
    for (int mt = 0; mt < 4; ++mt) {
        #pragma unroll
        for (int r = 0; r < 4; ++r) {
            int rowc = m0 + wm * 64 + mt * 16 + (lane >> 4) * 4 + r;
            if (rowc < M) {
                #pragma unroll
                for (int nt = 0; nt < 4; ++nt) {
                    int col = n0 + wn * 64 + nt * 16 + (lane & 15);
                    float v = acc[mt][nt][r];
                    C[(size_t)rowc * N + col] = __float2bfloat16(v);
                    __hip_fp8_e4m3 q8(v);
                    C8[(size_t)rowc * N + col] = q8.__x;
                }
            }
        }
    }
}

// ---------------- attention scores: as/ad[n,h] = sum_o h[n,h,o]*att[h,o] ----------------
__global__ __launch_bounds__(256) void attn_score(const __hip_bfloat16* __restrict__ h,
                                                  const float* __restrict__ att_src,
                                                  const float* __restrict__ att_dst,
                                                  float* __restrict__ as_,
                                                  float* __restrict__ ad_) {
    int wave = threadIdx.x >> 6, lane = threadIdx.x & 63;
    int node = blockIdx.x * 4 + wave;
    if (node >= NN || lane >= NH) return;
    const bf16x8* hp = (const bf16x8*)(h + (size_t)node * DD1 + lane * OC);
    float s = 0.f, d = 0.f;
    #pragma unroll
    for (int jj = 0; jj < 4; ++jj) {
        bf16x8 hv = hp[jj];
        #pragma unroll
        for (int j = 0; j < 8; ++j) {
            float v = (float)hv[j];
            int o = jj * 8 + j;
            s += v * att_src[lane * OC + o];
            d += v * att_dst[lane * OC + o];
        }
    }
    as_[node * NH + lane] = s;
    ad_[node * NH + lane] = d;
}

// ---------------- fused per-dst score + softmax -> bf16 alpha ----------------
__global__ __launch_bounds__(256) void score_softmax(const int* __restrict__ rowptr,
                                                     const int* __restrict__ csr_src,
                                                     const float* __restrict__ as_,
                                                     const float* __restrict__ ad_,
                                                     __hip_bfloat16* __restrict__ alpha) {
    int wave = threadIdx.x >> 6, lane = threadIdx.x & 63;
    int node = blockIdx.x * 4 + wave;
    if (node >= NN || lane >= NH) return;
    int e0 = rowptr[node], e1 = rowptr[node + 1];
    float adv = ad_[(size_t)node * NH + lane];

    float m = -1e30f;
    for (int e = e0; e < e1; ++e) {
        int s = csr_src[e];
        float v = as_[(size_t)s * NH + lane] + adv;
        v = v > 0.f ? v : 0.2f * v;
        m = fmaxf(m, v);
    }
    float den = 0.f;
    for (int e = e0; e < e1; ++e) {
        int s = csr_src[e];
        float v = as_[(size_t)s * NH + lane] + adv;
        v = v > 0.f ? v : 0.2f * v;
        den += __expf(v - m);
    }
    float inv = 1.f / den;
    for (int e = e0; e < e1; ++e) {
        int s = csr_src[e];
        float v = as_[(size_t)s * NH + lane] + adv;
        v = v > 0.f ? v : 0.2f * v;
        alpha[(size_t)e * NH + lane] = __float2bfloat16(__expf(v - m) * inv);
    }
}

// ---------------- node-boundary flush for the streaming aggregate ----------------
// LAYER==1: bf16 h1p[cur][slice] = BN1(ELU(acc + b1))
// LAYER==2: head-reduce in-wave, atomicAdd head-mean partials into fp32 h2s[cur][32]
template <int LAYER>
__device__ __forceinline__ void flush_node(float* acc, int cur, int f, int lane,
                                           const float* __restrict__ bias,
                                           const float* __restrict__ bng,
                                           const float* __restrict__ bnb,
                                           const float* __restrict__ bnm,
                                           const float* __restrict__ bnv,
                                           void* __restrict__ outp) {
    if constexpr (LAYER == 1) {
        int d0 = f * 256 + lane * 4;
        u32 r01, r23;
        {
            float v0 = acc[0] + bias[d0 + 0];
            float v1 = acc[1] + bias[d0 + 1];
            float v2 = acc[2] + bias[d0 + 2];
            float v3 = acc[3] + bias[d0 + 3];
            v0 = v0 > 0.f ? v0 : expm1f(v0);
            v1 = v1 > 0.f ? v1 : expm1f(v1);
            v2 = v2 > 0.f ? v2 : expm1f(v2);
            v3 = v3 > 0.f ? v3 : expm1f(v3);
            v0 = (v0 - bnm[d0 + 0]) * rsqrtf(bnv[d0 + 0] + EPS_BN) * bng[d0 + 0] + bnb[d0 + 0];
            v1 = (v1 - bnm[d0 + 1]) * rsqrtf(bnv[d0 + 1] + EPS_BN) * bng[d0 + 1] + bnb[d0 + 1];
            v2 = (v2 - bnm[d0 + 2]) * rsqrtf(bnv[d0 + 2] + EPS_BN) * bng[d0 + 2] + bnb[d0 + 2];
            v3 = (v3 - bnm[d0 + 3]) * rsqrtf(bnv[d0 + 3] + EPS_BN) * bng[d0 + 3] + bnb[d0 + 3];
            __hip_bfloat16 b0 = __float2bfloat16(v0), b1 = __float2bfloat16(v1);
            __hip_bfloat16 b2 = __float2bfloat16(v2), b3 = __float2bfloat16(v3);
            r01 = (u32)*(unsigned short*)&b0 | ((u32)*(unsigned short*)&b1 << 16);
            r23 = (u32)*(unsigned short*)&b2 | ((u32)*(unsigned short*)&b3 << 16);
        }
        uint2 pk; pk.x = r01; pk.y = r23;
        *(uint2*)((__hip_bfloat16*)outp + (size_t)cur * DD1 + d0) = pk;
    } else {
        // sum over the 8 heads held by this wave (lane groups stride 8)
        #pragma unroll
        for (int k = 0; k < 4; ++k) {
            acc[k] += __shfl_xor(acc[k], 8, 64);
            acc[k] += __shfl_xor(acc[k], 16, 64);
            acc[k] += __shfl_xor(acc[k], 32, 64);
        }
        if (lane < 8) {
            #pragma unroll
            for (int k = 0; k < 4; ++k)
                atomicAdd((float*)outp + (size_t)cur * OC + lane * 4 + k, acc[k] * (1.f / NH));
        }
    }
    acc[0] = acc[1] = acc[2] = acc[3] = 0.f;
}

// ---------------- streaming slice-parallel aggregation ----------------
// wave = (slice f in [0,7), node group of GRP nodes). Lane covers 4 fp8 features
// at byte offset f*256 + lane*4. Streams the group's CSR-contiguous edges in
// batches of EB clamp-padded (unconditional) loads; flushes acc at node bounds.
template <int LAYER>
__global__ __launch_bounds__(256) void attn_aggregate(const int* __restrict__ rowptr,
                                                      const int* __restrict__ csr_src,
                                                      const __hip_bfloat16* __restrict__ alpha,
                                                      const unsigned char* __restrict__ h8,
                                                      const float* __restrict__ bias,
                                                      const float* __restrict__ bng,
                                                      const float* __restrict__ bnb,
                                                      const float* __restrict__ bnm,
                                                      const float* __restrict__ bnv,
                                                      void* __restrict__ outp) {
    const int wv = threadIdx.x >> 6, lane = threadIdx.x & 63;
    const int w = blockIdx.x * 4 + wv;
    const int NWAVES = 7 * (NN / GRP);
    if (w >= NWAVES) return;
    const int f  = w % 7;             // feature slice (256 B of the 1792-B row)
    const int g  = w / 7;             // node group
    const int n0 = g * GRP;
    const int off  = f * 256 + lane * 4;
    const int head = f * 8 + (lane >> 3);

    const int e0 = rowptr[n0], e1 = rowptr[n0 + GRP];
    int cur = n0;
    int bound = rowptr[n0 + 1];

    float acc[4] = {0.f, 0.f, 0.f, 0.f};

    for (int e = e0; e < e1; e += EB) {
        u32   hv[EB];
        float av[EB];
        // unconditional clamp-padded loads: EB independent chains in flight
        #pragma unroll
        for (int i = 0; i < EB; ++i) {
            int idx = (e + i < e1) ? e + i : e1 - 1;
            int s = csr_src[idx];
            hv[i] = *(const u32*)(h8 + (size_t)s * DD1 + off);
            float a = (float)alpha[(size_t)idx * NH + head];
            av[i] = (e + i < e1) ? a : 0.f;   // padded edges contribute 0
        }
        #pragma unroll
        for (int i = 0; i < EB; ++i) {
            if (e + i >= bound && e + i < e1) {   // crossed into next node
                flush_node<LAYER>(acc, cur, f, lane, bias, bng, bnb, bnm, bnv, outp);
                ++cur;
                bound = rowptr[cur + 1];
            }
            fma_fp8x4(hv[i], av[i], acc);
        }
    }
    flush_node<LAYER>(acc, cur, f, lane, bias, bng, bnb, bnm, bnv, outp);
}

// ---------------- mean pool (atomics) ----------------
__global__ __launch_bounds__(256) void pool_kernel(const float* __restrict__ h2s,
                                                   const int* __restrict__ batch,
                                                   float* __restrict__ sums,
                                                   float* __restrict__ cnt) {
    int gid = blockIdx.x * 256 + threadIdx.x;
    if (gid >= NN * OC) return;
    int node = gid >> 5, ch = gid & 31;
    int g = batch[node];
    atomicAdd(&sums[g * OC + ch], h2s[gid]);
    if (ch == 0) atomicAdd(&cnt[g], 1.0f);
}

// final: pooled = sums/cnt; v = BN2(pooled + b2); out = v @ lin_w + lin_b
__global__ __launch_bounds__(128) void final_kernel(const float* __restrict__ sums,
                                                    const float* __restrict__ cnt,
                                                    const float* __restrict__ b2,
                                                    const float* __restrict__ bn2g,
                                                    const float* __restrict__ bn2b,
                                                    const float* __restrict__ bn2m,
                                                    const float* __restrict__ bn2v,
                                                    const float* __restrict__ lin_w,
                                                    const float* __restrict__ lin_b,
                                                    float* __restrict__ out) {
    int t = threadIdx.x;
    if (t >= NG * 2) return;
    int g = t >> 1, c = t & 1;
    float invc = 1.f / fmaxf(cnt[g], 1.f);
    float acc = lin_b[c];
    #pragma unroll
    for (int o = 0; o < OC; ++o) {
        float pooled = sums[g * OC + o] * invc + b2[o];
        float v = (pooled - bn2m[o]) * rsqrtf(bn2v[o] + EPS_BN) * bn2g[o] + bn2b[o];
        acc += v * lin_w[o * 2 + c];
    }
    out[t] = acc;
}

// ---------------- host-side launch ----------------
extern "C" void kernel_launch(void* const* d_in, const int* in_sizes, int n_in,
                              void* d_out, int out_size, void* d_ws, size_t ws_size,
                              hipStream_t stream) {
    const float* x    = (const float*)d_in[0];
    const int*   ei   = (const int*)d_in[1];
    const int*   bat  = (const int*)d_in[2];
    const float* W1   = (const float*)d_in[3];
    const float* at_s1 = (const float*)d_in[4];
    const float* at_d1 = (const float*)d_in[5];
    const float* b1   = (const float*)d_in[6];
    const float* bn1g = (const float*)d_in[7];
    const float* bn1b = (const float*)d_in[8];
    const float* bn1m = (const float*)d_in[9];
    const float* bn1v = (const float*)d_in[10];
    const float* W2   = (const float*)d_in[11];
    const float* at_s2 = (const float*)d_in[12];
    const float* at_d2 = (const float*)d_in[13];
    const float* b2   = (const float*)d_in[14];
    const float* bn2g = (const float*)d_in[15];
    const float* bn2b = (const float*)d_in[16];
    const float* bn2m = (const float*)d_in[17];
    const float* bn2v = (const float*)d_in[18];
    const float* linw = (const float*)d_in[19];
    const float* linb = (const float*)d_in[20];
    float* out = (float*)d_out;

    char* wsp = (char*)d_ws;
    auto alloc = [&](size_t bytes) -> void* {
        void* p = (void*)wsp;
        wsp += (bytes + 255) & ~(size_t)255;
        return p;
    };
    __hip_bfloat16* h1  = (__hip_bfloat16*)alloc((size_t)NN * DD1 * 2);  // reused as h2
    unsigned char*  h8  = (unsigned char*)alloc((size_t)NN * DD1);      // fp8 copy
    __hip_bfloat16* h1p = (__hip_bfloat16*)alloc((size_t)NN * DD1 * 2);
    __hip_bfloat16* xb  = (__hip_bfloat16*)alloc((size_t)NN * NF * 2);
    __hip_bfloat16* w1t = (__hip_bfloat16*)alloc((size_t)DD1 * NF * 2);
    __hip_bfloat16* w2t = (__hip_bfloat16*)alloc((size_t)DD1 * DD1 * 2);
    float* asb   = (float*)alloc((size_t)NN * NH * 4);
    float* adb   = (float*)alloc((size_t)NN * NH * 4);
    int*   deg   = (int*)alloc((size_t)NN * 4);
    int*   rowp  = (int*)alloc((size_t)(NN + 1) * 4);
    int*   curs  = (int*)alloc((size_t)NN * 4);
    int*   csr   = (int*)alloc((size_t)ETOT * 4);
    __hip_bfloat16* alp = (__hip_bfloat16*)alloc((size_t)ETOT * NH * 2);
    float* h2s   = (float*)alloc((size_t)NN * OC * 4);
    float* sums  = (float*)alloc((size_t)(NG * OC + NG) * 4);
    float* cnt   = sums + NG * OC;

    hipMemsetAsync(deg, 0, (size_t)NN * 4, stream);
    hipMemsetAsync(h2s, 0, (size_t)NN * OC * 4, stream);
    hipMemsetAsync(sums, 0, (size_t)(NG * OC + NG) * 4, stream);

    cast_bf16_kernel<<<(NN * NF + 255) / 256, 256, 0, stream>>>(x, xb, NN * NF);
    transpose_cast_kernel<<<dim3(DD1 / 32, NF / 32), 256, 0, stream>>>(W1, w1t, NF, DD1);
    transpose_cast_kernel<<<dim3(DD1 / 32, DD1 / 32), 256, 0, stream>>>(W2, w2t, DD1, DD1);
    hist_kernel<<<(ETOT + 255) / 256, 256, 0, stream>>>(ei, deg);
    scan_kernel<<<1, 1024, 0, stream>>>(deg, rowp, curs);
    scatter_kernel<<<(ETOT + 255) / 256, 256, 0, stream>>>(ei, curs, csr);

    const int AGG_BLOCKS = (7 * (NN / GRP) + 3) / 4;

    // layer 1
    gemm_bf16<<<dim3(DD1 / 128, (NN + 127) / 128), 256, 0, stream>>>(xb, w1t, h1, h8, NN, DD1, NF);
    attn_score<<<NN / 4, 256, 0, stream>>>(h1, at_s1, at_d1, asb, adb);
    score_softmax<<<NN / 4, 256, 0, stream>>>(rowp, csr, asb, adb, alp);
    attn_aggregate<1><<<AGG_BLOCKS, 256, 0, stream>>>(rowp, csr, alp, h8, b1, bn1g, bn1b, bn1m, bn1v, (void*)h1p);

    // layer 2
    gemm_bf16<<<dim3(DD1 / 128, (NN + 127) / 128), 256, 0, stream>>>(h1p, w2t, h1, h8, NN, DD1, DD1);
    attn_score<<<NN / 4, 256, 0, stream>>>(h1, at_s2, at_d2, asb, adb);
    score_softmax<<<NN / 4, 256, 0, stream>>>(rowp, csr, asb, adb, alp);
    attn_aggregate<2><<<AGG_BLOCKS, 256, 0, stream>>>(rowp, csr, alp, h8, b2, bn2g, bn2b, bn2m, bn2v, (void*)h2s);

    pool_kernel<<<(NN * OC) / 256, 256, 0, stream>>>(h2s, bat, sums, cnt);
    final_kernel<<<1, 128, 0, stream>>>(sums, cnt, b2, bn2g, bn2b, bn2m, bn2v, linw, linb, out);
}

// Round 7
// 815.232 us; speedup vs baseline: 1.3235x; 1.0256x over previous
//
#include <hip/hip_runtime.h>
#include <hip/hip_bf16.h>
#include <hip/hip_fp8.h>
#include <cstdint>
#include <cstddef>

// Problem constants
#define NN     20000     // nodes
#define NF     128       // in features
#define NH     56        // heads
#define OC     32        // out channels per head
#define DD1    1792      // NH*OC
#define NE     100000    // edges (before self loops)
#define ETOT   120000    // edges + self loops
#define NG     50        // graphs
#define EPS_BN 1e-5f
#define GRP    16        // nodes per wave in aggregate
#define EB     16        // edge batch (loads in flight)

typedef __bf16 bf16x8 __attribute__((ext_vector_type(8)));
typedef float  floatx4 __attribute__((ext_vector_type(4)));
typedef unsigned int u32;
typedef __attribute__((address_space(1))) u32 gu32;
typedef __attribute__((address_space(3))) u32 lu32;

__device__ __forceinline__ void async_copy16(void* lds, const void* g) {
    __builtin_amdgcn_global_load_lds((gu32*)const_cast<void*>(g), (lu32*)lds, 16, 0, 0);
}

// decode 4 fp8 (e4m3, packed in u32) and accumulate a*val into acc[0..3]
__device__ __forceinline__ void fma_fp8x4(u32 u, float a, float* acc) {
    #pragma unroll
    for (int b = 0; b < 4; ++b) {
        __hip_fp8_e4m3 t;
        t.__x = (u >> (8 * b)) & 0xff;
        acc[b] += a * (float)t;
    }
}

// ---------------- elementwise cast fp32 -> bf16 ----------------
__global__ __launch_bounds__(256) void cast_bf16_kernel(const float* __restrict__ in,
                                                        __hip_bfloat16* __restrict__ out, int n) {
    int i = blockIdx.x * 256 + threadIdx.x;
    if (i < n) out[i] = __float2bfloat16(in[i]);
}

// ---------------- tiled transpose + cast: in[R][C] f32 -> out[C][R] bf16 ----------------
__global__ __launch_bounds__(256) void transpose_cast_kernel(const float* __restrict__ in,
                                                             __hip_bfloat16* __restrict__ out,
                                                             int R, int C) {
    __shared__ float tile[32][33];
    int c0 = blockIdx.x * 32, r0 = blockIdx.y * 32;
    int tx = threadIdx.x & 31, ty = threadIdx.x >> 5;   // ty in 0..7
    #pragma unroll
    for (int i = 0; i < 32; i += 8) {
        int r = r0 + ty + i, c = c0 + tx;
        if (r < R && c < C) tile[ty + i][tx] = in[(size_t)r * C + c];
    }
    __syncthreads();
    #pragma unroll
    for (int i = 0; i < 32; i += 8) {
        int c = c0 + ty + i, r = r0 + tx;
        if (c < C && r < R) out[(size_t)c * R + r] = __float2bfloat16(tile[tx][ty + i]);
    }
}

// ---------------- CSR build: histogram / scan / scatter ----------------
__global__ __launch_bounds__(256) void hist_kernel(const int* __restrict__ ei, int* __restrict__ deg) {
    int i = blockIdx.x * 256 + threadIdx.x;
    if (i >= ETOT) return;
    int dst = (i < NE) ? ei[NE + i] : (i - NE);
    atomicAdd(&deg[dst], 1);
}

__global__ __launch_bounds__(1024) void scan_kernel(const int* __restrict__ deg,
                                                    int* __restrict__ rowptr,
                                                    int* __restrict__ cursor) {
    __shared__ int buf[1024];
    int t = threadIdx.x;
    const int CH = (NN + 1023) >> 10;   // 20
    int base = t * CH;
    int s = 0;
    for (int j = 0; j < CH; ++j) { int idx = base + j; if (idx < NN) s += deg[idx]; }
    buf[t] = s;
    __syncthreads();
    for (int off = 1; off < 1024; off <<= 1) {
        int v = (t >= off) ? buf[t - off] : 0;
        __syncthreads();
        buf[t] += v;
        __syncthreads();
    }
    int run = buf[t] - s;   // exclusive
    for (int j = 0; j < CH; ++j) {
        int idx = base + j;
        if (idx < NN) { rowptr[idx] = run; cursor[idx] = run; run += deg[idx]; }
    }
    if (t == 1023) rowptr[NN] = buf[1023];
}

__global__ __launch_bounds__(256) void scatter_kernel(const int* __restrict__ ei,
                                                      int* __restrict__ cursor,
                                                      int* __restrict__ csr_src) {
    int i = blockIdx.x * 256 + threadIdx.x;
    if (i >= ETOT) return;
    int s, d;
    if (i < NE) { s = ei[i]; d = ei[NE + i]; } else { s = i - NE; d = i - NE; }
    int pos = atomicAdd(&cursor[d], 1);
    csr_src[pos] = s;
}

// ---------------- bf16 MFMA GEMM: C = A * Bt^T, writes bf16 C AND fp8 C8 ----------------
// 1D grid with XCD-locality swizzle: xcd c = id%8 owns A-panel stripe by = c+8q,
// iterating the 14 N-tiles in two halves of 7 (A-panel + B-half < 4 MB L2).
__global__ __launch_bounds__(256) void gemm_bf16(const __hip_bfloat16* __restrict__ A,
                                                 const __hip_bfloat16* __restrict__ Bt,
                                                 __hip_bfloat16* __restrict__ C,
                                                 unsigned char* __restrict__ C8,
                                                 int M, int N, int K) {
    __shared__ __align__(16) unsigned short lsA[128 * 32];
    __shared__ __align__(16) unsigned short lsB[128 * 32];
    const int tid  = threadIdx.x;
    const int lane = tid & 63, wave = tid >> 6;
    const int wm = wave >> 1, wn = wave & 1;

    // swizzle: nbx = N/128 (14), halfw = 7, nq = ceil(nby/8)
    const int nbx = N >> 7;
    const int halfw = nbx >> 1;
    const int nby = (M + 127) >> 7;
    const int nq = (nby + 7) >> 3;
    const int c = blockIdx.x & 7;
    int j = blockIdx.x >> 3;
    const int half = j / (halfw * nq);
    j -= half * halfw * nq;
    const int q = j / halfw;
    const int k = j - q * halfw;
    const int by = c + 8 * q;
    const int bx = half * halfw + k;
    if (by >= nby) return;
    const int m0 = by * 128, n0 = bx * 128;

    floatx4 zero = {0.f, 0.f, 0.f, 0.f};
    floatx4 acc[4][4];
    #pragma unroll
    for (int i = 0; i < 4; ++i)
        #pragma unroll
        for (int jj = 0; jj < 4; ++jj) acc[i][jj] = zero;

    for (int k0 = 0; k0 < K; k0 += 32) {
        #pragma unroll
        for (int i = 0; i < 2; ++i) {
            int slot = tid + i * 256;
            int row = slot >> 2, seg = slot & 3;
            int gseg = seg ^ ((row >> 1) & 3);
            int gr = m0 + row; if (gr > M - 1) gr = M - 1;
            async_copy16(&lsA[slot * 8], A + (size_t)gr * K + k0 + gseg * 8);
        }
        #pragma unroll
        for (int i = 0; i < 2; ++i) {
            int slot = tid + i * 256;
            int row = slot >> 2, seg = slot & 3;
            int gseg = seg ^ ((row >> 1) & 3);
            async_copy16(&lsB[slot * 8], Bt + (size_t)(n0 + row) * K + k0 + gseg * 8);
        }
        __syncthreads();

        bf16x8 aF[4], bF[4];
        const int qq = lane >> 4;
        #pragma unroll
        for (int mt = 0; mt < 4; ++mt) {
            int row = wm * 64 + mt * 16 + (lane & 15);
            int seg = qq ^ ((row >> 1) & 3);
            aF[mt] = *(const bf16x8*)&lsA[row * 32 + seg * 8];
        }
        #pragma unroll
        for (int nt = 0; nt < 4; ++nt) {
            int row = wn * 64 + nt * 16 + (lane & 15);
            int seg = qq ^ ((row >> 1) & 3);
            bF[nt] = *(const bf16x8*)&lsB[row * 32 + seg * 8];
        }
        #pragma unroll
        for (int mt = 0; mt < 4; ++mt)
            #pragma unroll
            for (int nt = 0; nt < 4; ++nt)
                acc[mt][nt] = __builtin_amdgcn_mfma_f32_16x16x32_bf16(aF[mt], bF[nt], acc[mt][nt], 0, 0, 0);
        __syncthreads();
    }

    #pragma unroll
    for (int mt = 0; mt < 4; ++mt) {
        #pragma unroll
        for (int r = 0; r < 4; ++r) {
            int rowc = m0 + wm * 64 + mt * 16 + (lane >> 4) * 4 + r;
            if (rowc < M) {
                float v0 = acc[mt][0][r], v1 = acc[mt][1][r];
                float v2 = acc[mt][2][r], v3 = acc[mt][3][r];
                unsigned char q8[4];
#if __has_builtin(__builtin_amdgcn_cvt_pk_fp8_f32)
                u32 p01 = (u32)__builtin_amdgcn_cvt_pk_fp8_f32(v0, v1, 0, false);
                u32 p23 = (u32)__builtin_amdgcn_cvt_pk_fp8_f32(v2, v3, 0, false);
                q8[0] = p01 & 0xff; q8[1] = (p01 >> 8) & 0xff;
                q8[2] = p23 & 0xff; q8[3] = (p23 >> 8) & 0xff;
#else
                { __hip_fp8_e4m3 t0(v0), t1(v1), t2(v2), t3(v3);
                  q8[0] = t0.__x; q8[1] = t1.__x; q8[2] = t2.__x; q8[3] = t3.__x; }
#endif
                float vv[4] = {v0, v1, v2, v3};
                #pragma unroll
                for (int nt = 0; nt < 4; ++nt) {
                    int col = n0 + wn * 64 + nt * 16 + (lane & 15);
                    C[(size_t)rowc * N + col] = __float2bfloat16(vv[nt]);
                    C8[(size_t)rowc * N + col] = q8[nt];
                }
            }
        }
    }
}

// ---------------- attention scores: as/ad[n,h] = sum_o h[n,h,o]*att[h,o] ----------------
__global__ __launch_bounds__(256) void attn_score(const __hip_bfloat16* __restrict__ h,
                                                  const float* __restrict__ att_src,
                                                  const float* __restrict__ att_dst,
                                                  float* __restrict__ as_,
                                                  float* __restrict__ ad_) {
    int wave = threadIdx.x >> 6, lane = threadIdx.x & 63;
    int node = blockIdx.x * 4 + wave;
    if (node >= NN || lane >= NH) return;
    const bf16x8* hp = (const bf16x8*)(h + (size_t)node * DD1 + lane * OC);
    float s = 0.f, d = 0.f;
    #pragma unroll
    for (int jj = 0; jj < 4; ++jj) {
        bf16x8 hv = hp[jj];
        #pragma unroll
        for (int j = 0; j < 8; ++j) {
            float v = (float)hv[j];
            int o = jj * 8 + j;
            s += v * att_src[lane * OC + o];
            d += v * att_dst[lane * OC + o];
        }
    }
    as_[node * NH + lane] = s;
    ad_[node * NH + lane] = d;
}

// ---------------- fused per-dst score + softmax -> bf16 alpha ----------------
__global__ __launch_bounds__(256) void score_softmax(const int* __restrict__ rowptr,
                                                     const int* __restrict__ csr_src,
                                                     const float* __restrict__ as_,
                                                     const float* __restrict__ ad_,
                                                     __hip_bfloat16* __restrict__ alpha) {
    int wave = threadIdx.x >> 6, lane = threadIdx.x & 63;
    int node = blockIdx.x * 4 + wave;
    if (node >= NN || lane >= NH) return;
    int e0 = rowptr[node], e1 = rowptr[node + 1];
    float adv = ad_[(size_t)node * NH + lane];

    float m = -1e30f;
    for (int e = e0; e < e1; ++e) {
        int s = csr_src[e];
        float v = as_[(size_t)s * NH + lane] + adv;
        v = v > 0.f ? v : 0.2f * v;
        m = fmaxf(m, v);
    }
    float den = 0.f;
    for (int e = e0; e < e1; ++e) {
        int s = csr_src[e];
        float v = as_[(size_t)s * NH + lane] + adv;
        v = v > 0.f ? v : 0.2f * v;
        den += __expf(v - m);
    }
    float inv = 1.f / den;
    for (int e = e0; e < e1; ++e) {
        int s = csr_src[e];
        float v = as_[(size_t)s * NH + lane] + adv;
        v = v > 0.f ? v : 0.2f * v;
        alpha[(size_t)e * NH + lane] = __float2bfloat16(__expf(v - m) * inv);
    }
}

// ---------------- node-boundary flush for the streaming aggregate ----------------
// LAYER==1: bf16 h1p[cur][slice] = BN1(ELU(acc + b1))
// LAYER==2: head-reduce in-wave, write per-slice partial (non-atomic) to h2part[cur][f][32]
template <int LAYER>
__device__ __forceinline__ void flush_node(float* acc, int cur, int f, int lane,
                                           const float* __restrict__ bias,
                                           const float* __restrict__ bng,
                                           const float* __restrict__ bnb,
                                           const float* __restrict__ bnm,
                                           const float* __restrict__ bnv,
                                           void* __restrict__ outp) {
    if constexpr (LAYER == 1) {
        int d0 = f * 256 + lane * 4;
        u32 r01, r23;
        {
            float v0 = acc[0] + bias[d0 + 0];
            float v1 = acc[1] + bias[d0 + 1];
            float v2 = acc[2] + bias[d0 + 2];
            float v3 = acc[3] + bias[d0 + 3];
            v0 = v0 > 0.f ? v0 : expm1f(v0);
            v1 = v1 > 0.f ? v1 : expm1f(v1);
            v2 = v2 > 0.f ? v2 : expm1f(v2);
            v3 = v3 > 0.f ? v3 : expm1f(v3);
            v0 = (v0 - bnm[d0 + 0]) * rsqrtf(bnv[d0 + 0] + EPS_BN) * bng[d0 + 0] + bnb[d0 + 0];
            v1 = (v1 - bnm[d0 + 1]) * rsqrtf(bnv[d0 + 1] + EPS_BN) * bng[d0 + 1] + bnb[d0 + 1];
            v2 = (v2 - bnm[d0 + 2]) * rsqrtf(bnv[d0 + 2] + EPS_BN) * bng[d0 + 2] + bnb[d0 + 2];
            v3 = (v3 - bnm[d0 + 3]) * rsqrtf(bnv[d0 + 3] + EPS_BN) * bng[d0 + 3] + bnb[d0 + 3];
            __hip_bfloat16 b0 = __float2bfloat16(v0), b1 = __float2bfloat16(v1);
            __hip_bfloat16 b2 = __float2bfloat16(v2), b3 = __float2bfloat16(v3);
            r01 = (u32)*(unsigned short*)&b0 | ((u32)*(unsigned short*)&b1 << 16);
            r23 = (u32)*(unsigned short*)&b2 | ((u32)*(unsigned short*)&b3 << 16);
        }
        uint2 pk; pk.x = r01; pk.y = r23;
        *(uint2*)((__hip_bfloat16*)outp + (size_t)cur * DD1 + d0) = pk;
    } else {
        // sum over the 8 heads held by this wave (lane groups stride 8)
        #pragma unroll
        for (int k = 0; k < 4; ++k) {
            acc[k] += __shfl_xor(acc[k], 8, 64);
            acc[k] += __shfl_xor(acc[k], 16, 64);
            acc[k] += __shfl_xor(acc[k], 32, 64);
        }
        if (lane < 8) {
            floatx4 pk;
            #pragma unroll
            for (int k = 0; k < 4; ++k) pk[k] = acc[k] * (1.f / NH);
            *(floatx4*)((float*)outp + ((size_t)cur * 7 + f) * OC + lane * 4) = pk;
        }
    }
    acc[0] = acc[1] = acc[2] = acc[3] = 0.f;
}

// ---------------- streaming slice-parallel aggregation ----------------
// wave = (slice f in [0,7), node group of GRP nodes). Lane covers 4 fp8 features
// at byte offset f*256 + lane*4. Streams the group's CSR-contiguous edges in
// batches of EB clamp-padded (unconditional) loads; flushes acc at node bounds.
template <int LAYER>
__global__ __launch_bounds__(256) void attn_aggregate(const int* __restrict__ rowptr,
                                                      const int* __restrict__ csr_src,
                                                      const __hip_bfloat16* __restrict__ alpha,
                                                      const unsigned char* __restrict__ h8,
                                                      const float* __restrict__ bias,
                                                      const float* __restrict__ bng,
                                                      const float* __restrict__ bnb,
                                                      const float* __restrict__ bnm,
                                                      const float* __restrict__ bnv,
                                                      void* __restrict__ outp) {
    const int wv = threadIdx.x >> 6, lane = threadIdx.x & 63;
    const int w = blockIdx.x * 4 + wv;
    const int NWAVES = 7 * (NN / GRP);
    if (w >= NWAVES) return;
    const int f  = w % 7;             // feature slice (256 B of the 1792-B row)
    const int g  = w / 7;             // node group
    const int n0 = g * GRP;
    const int off  = f * 256 + lane * 4;
    const int head = f * 8 + (lane >> 3);

    const int e0 = rowptr[n0], e1 = rowptr[n0 + GRP];
    int cur = n0;
    int bound = rowptr[n0 + 1];

    float acc[4] = {0.f, 0.f, 0.f, 0.f};

    for (int e = e0; e < e1; e += EB) {
        u32   hv[EB];
        float av[EB];
        // unconditional clamp-padded loads: EB independent chains in flight
        #pragma unroll
        for (int i = 0; i < EB; ++i) {
            int idx = (e + i < e1) ? e + i : e1 - 1;
            int s = csr_src[idx];
            hv[i] = *(const u32*)(h8 + (size_t)s * DD1 + off);
            float a = (float)alpha[(size_t)idx * NH + head];
            av[i] = (e + i < e1) ? a : 0.f;   // padded edges contribute 0
        }
        #pragma unroll
        for (int i = 0; i < EB; ++i) {
            if (e + i >= bound && e + i < e1) {   // crossed into next node
                flush_node<LAYER>(acc, cur, f, lane, bias, bng, bnb, bnm, bnv, outp);
                ++cur;
                bound = rowptr[cur + 1];
            }
            fma_fp8x4(hv[i], av[i], acc);
        }
    }
    flush_node<LAYER>(acc, cur, f, lane, bias, bng, bnb, bnm, bnv, outp);
}

// ---------------- mean pool: sum 7 slice-partials, atomic into graph sums ----------------
__global__ __launch_bounds__(256) void pool_kernel(const float* __restrict__ h2part,
                                                   const int* __restrict__ batch,
                                                   float* __restrict__ sums,
                                                   float* __restrict__ cnt) {
    int gid = blockIdx.x * 256 + threadIdx.x;
    if (gid >= NN * OC) return;
    int node = gid >> 5, ch = gid & 31;
    float v = 0.f;
    #pragma unroll
    for (int f = 0; f < 7; ++f) v += h2part[((size_t)node * 7 + f) * OC + ch];
    int g = batch[node];
    atomicAdd(&sums[g * OC + ch], v);
    if (ch == 0) atomicAdd(&cnt[g], 1.0f);
}

// final: pooled = sums/cnt; v = BN2(pooled + b2); out = v @ lin_w + lin_b
__global__ __launch_bounds__(128) void final_kernel(const float* __restrict__ sums,
                                                    const float* __restrict__ cnt,
                                                    const float* __restrict__ b2,
                                                    const float* __restrict__ bn2g,
                                                    const float* __restrict__ bn2b,
                                                    const float* __restrict__ bn2m,
                                                    const float* __restrict__ bn2v,
                                                    const float* __restrict__ lin_w,
                                                    const float* __restrict__ lin_b,
                                                    float* __restrict__ out) {
    int t = threadIdx.x;
    if (t >= NG * 2) return;
    int g = t >> 1, c = t & 1;
    float invc = 1.f / fmaxf(cnt[g], 1.f);
    float acc = lin_b[c];
    #pragma unroll
    for (int o = 0; o < OC; ++o) {
        float pooled = sums[g * OC + o] * invc + b2[o];
        float v = (pooled - bn2m[o]) * rsqrtf(bn2v[o] + EPS_BN) * bn2g[o] + bn2b[o];
        acc += v * lin_w[o * 2 + c];
    }
    out[t] = acc;
}

// ---------------- host-side launch ----------------
extern "C" void kernel_launch(void* const* d_in, const int* in_sizes, int n_in,
                              void* d_out, int out_size, void* d_ws, size_t ws_size,
                              hipStream_t stream) {
    const float* x    = (const float*)d_in[0];
    const int*   ei   = (const int*)d_in[1];
    const int*   bat  = (const int*)d_in[2];
    const float* W1   = (const float*)d_in[3];
    const float* at_s1 = (const float*)d_in[4];
    const float* at_d1 = (const float*)d_in[5];
    const float* b1   = (const float*)d_in[6];
    const float* bn1g = (const float*)d_in[7];
    const float* bn1b = (const float*)d_in[8];
    const float* bn1m = (const float*)d_in[9];
    const float* bn1v = (const float*)d_in[10];
    const float* W2   = (const float*)d_in[11];
    const float* at_s2 = (const float*)d_in[12];
    const float* at_d2 = (const float*)d_in[13];
    const float* b2   = (const float*)d_in[14];
    const float* bn2g = (const float*)d_in[15];
    const float* bn2b = (const float*)d_in[16];
    const float* bn2m = (const float*)d_in[17];
    const float* bn2v = (const float*)d_in[18];
    const float* linw = (const float*)d_in[19];
    const float* linb = (const float*)d_in[20];
    float* out = (float*)d_out;

    char* wsp = (char*)d_ws;
    auto alloc = [&](size_t bytes) -> void* {
        void* p = (void*)wsp;
        wsp += (bytes + 255) & ~(size_t)255;
        return p;
    };
    __hip_bfloat16* h1  = (__hip_bfloat16*)alloc((size_t)NN * DD1 * 2);  // reused as h2
    unsigned char*  h8  = (unsigned char*)alloc((size_t)NN * DD1);      // fp8 copy
    __hip_bfloat16* h1p = (__hip_bfloat16*)alloc((size_t)NN * DD1 * 2);
    __hip_bfloat16* xb  = (__hip_bfloat16*)alloc((size_t)NN * NF * 2);
    __hip_bfloat16* w1t = (__hip_bfloat16*)alloc((size_t)DD1 * NF * 2);
    __hip_bfloat16* w2t = (__hip_bfloat16*)alloc((size_t)DD1 * DD1 * 2);
    float* asb   = (float*)alloc((size_t)NN * NH * 4);
    float* adb   = (float*)alloc((size_t)NN * NH * 4);
    int*   deg   = (int*)alloc((size_t)NN * 4);
    int*   rowp  = (int*)alloc((size_t)(NN + 1) * 4);
    int*   curs  = (int*)alloc((size_t)NN * 4);
    int*   csr   = (int*)alloc((size_t)ETOT * 4);
    __hip_bfloat16* alp = (__hip_bfloat16*)alloc((size_t)ETOT * NH * 2);
    float* h2part = (float*)alloc((size_t)NN * 7 * OC * 4);
    float* sums  = (float*)alloc((size_t)(NG * OC + NG) * 4);
    float* cnt   = sums + NG * OC;

    hipMemsetAsync(deg, 0, (size_t)NN * 4, stream);
    hipMemsetAsync(sums, 0, (size_t)(NG * OC + NG) * 4, stream);

    cast_bf16_kernel<<<(NN * NF + 255) / 256, 256, 0, stream>>>(x, xb, NN * NF);
    transpose_cast_kernel<<<dim3(DD1 / 32, NF / 32), 256, 0, stream>>>(W1, w1t, NF, DD1);
    transpose_cast_kernel<<<dim3(DD1 / 32, DD1 / 32), 256, 0, stream>>>(W2, w2t, DD1, DD1);
    hist_kernel<<<(ETOT + 255) / 256, 256, 0, stream>>>(ei, deg);
    scan_kernel<<<1, 1024, 0, stream>>>(deg, rowp, curs);
    scatter_kernel<<<(ETOT + 255) / 256, 256, 0, stream>>>(ei, curs, csr);

    const int AGG_BLOCKS = (7 * (NN / GRP) + 3) / 4;
    // swizzled 1D GEMM grid: 8 xcds * 2 halves * ceil(157/8) q-slots * 7 bx
    const int NBY = (NN + 127) / 128;           // 157
    const int GEMM_BLOCKS = 8 * 2 * ((NBY + 7) / 8) * 7;   // 2240

    // layer 1
    gemm_bf16<<<GEMM_BLOCKS, 256, 0, stream>>>(xb, w1t, h1, h8, NN, DD1, NF);
    attn_score<<<NN / 4, 256, 0, stream>>>(h1, at_s1, at_d1, asb, adb);
    score_softmax<<<NN / 4, 256, 0, stream>>>(rowp, csr, asb, adb, alp);
    attn_aggregate<1><<<AGG_BLOCKS, 256, 0, stream>>>(rowp, csr, alp, h8, b1, bn1g, bn1b, bn1m, bn1v, (void*)h1p);

    // layer 2
    gemm_bf16<<<GEMM_BLOCKS, 256, 0, stream>>>(h1p, w2t, h1, h8, NN, DD1, DD1);
    attn_score<<<NN / 4, 256, 0, stream>>>(h1, at_s2, at_d2, asb, adb);
    score_softmax<<<NN / 4, 256, 0, stream>>>(rowp, csr, asb, adb, alp);
    attn_aggregate<2><<<AGG_BLOCKS, 256, 0, stream>>>(rowp, csr, alp, h8, b2, bn2g, bn2b, bn2m, bn2v, (void*)h2part);

    pool_kernel<<<(NN * OC) / 256, 256, 0, stream>>>(h2part, bat, sums, cnt);
    final_kernel<<<1, 128, 0, stream>>>(sums, cnt, b2, bn2g, bn2b, bn2m, bn2v, linw, linb, out);
}

// Round 8
// 759.210 us; speedup vs baseline: 1.4211x; 1.0738x over previous
//
#include <hip/hip_runtime.h>
#include <hip/hip_bf16.h>
#include <hip/hip_fp8.h>
#include <cstdint>
#include <cstddef>

// Problem constants
#define NN     20000     // nodes
#define NF     128       // in features
#define NH     56        // heads
#define OC     32        // out channels per head
#define DD1    1792      // NH*OC
#define NE     100000    // edges (before self loops)
#define ETOT   120000    // edges + self loops
#define NG     50        // graphs
#define EPS_BN 1e-5f
#define GRP    16        // nodes per wave in aggregate
#define EB     16        // edge batch (aggregate loads in flight)
#define SB     8         // edge batch (softmax gather)

typedef __bf16 bf16x8 __attribute__((ext_vector_type(8)));
typedef float  floatx4 __attribute__((ext_vector_type(4)));
typedef unsigned int u32;
typedef __attribute__((address_space(1))) u32 gu32;
typedef __attribute__((address_space(3))) u32 lu32;

__device__ __forceinline__ void async_copy16(void* lds, const void* g) {
    __builtin_amdgcn_global_load_lds((gu32*)const_cast<void*>(g), (lu32*)lds, 16, 0, 0);
}

// decode 4 fp8 (e4m3, packed in u32) and accumulate a*val into acc[0..3]
__device__ __forceinline__ void fma_fp8x4(u32 u, float a, float* acc) {
    #pragma unroll
    for (int b = 0; b < 4; ++b) {
        __hip_fp8_e4m3 t;
        t.__x = (u >> (8 * b)) & 0xff;
        acc[b] += a * (float)t;
    }
}

// ---------------- elementwise cast fp32 -> bf16 ----------------
__global__ __launch_bounds__(256) void cast_bf16_kernel(const float* __restrict__ in,
                                                        __hip_bfloat16* __restrict__ out, int n) {
    int i = blockIdx.x * 256 + threadIdx.x;
    if (i < n) out[i] = __float2bfloat16(in[i]);
}

// ---------------- tiled transpose + cast: in[R][C] f32 -> out[C][R] bf16 ----------------
__global__ __launch_bounds__(256) void transpose_cast_kernel(const float* __restrict__ in,
                                                             __hip_bfloat16* __restrict__ out,
                                                             int R, int C) {
    __shared__ float tile[32][33];
    int c0 = blockIdx.x * 32, r0 = blockIdx.y * 32;
    int tx = threadIdx.x & 31, ty = threadIdx.x >> 5;   // ty in 0..7
    #pragma unroll
    for (int i = 0; i < 32; i += 8) {
        int r = r0 + ty + i, c = c0 + tx;
        if (r < R && c < C) tile[ty + i][tx] = in[(size_t)r * C + c];
    }
    __syncthreads();
    #pragma unroll
    for (int i = 0; i < 32; i += 8) {
        int c = c0 + ty + i, r = r0 + tx;
        if (c < C && r < R) out[(size_t)c * R + r] = __float2bfloat16(tile[tx][ty + i]);
    }
}

// ---------------- CSR build: histogram / scan / scatter ----------------
__global__ __launch_bounds__(256) void hist_kernel(const int* __restrict__ ei, int* __restrict__ deg) {
    int i = blockIdx.x * 256 + threadIdx.x;
    if (i >= ETOT) return;
    int dst = (i < NE) ? ei[NE + i] : (i - NE);
    atomicAdd(&deg[dst], 1);
}

__global__ __launch_bounds__(1024) void scan_kernel(const int* __restrict__ deg,
                                                    int* __restrict__ rowptr,
                                                    int* __restrict__ cursor) {
    __shared__ int buf[1024];
    int t = threadIdx.x;
    const int CH = (NN + 1023) >> 10;   // 20
    int base = t * CH;
    int s = 0;
    for (int j = 0; j < CH; ++j) { int idx = base + j; if (idx < NN) s += deg[idx]; }
    buf[t] = s;
    __syncthreads();
    for (int off = 1; off < 1024; off <<= 1) {
        int v = (t >= off) ? buf[t - off] : 0;
        __syncthreads();
        buf[t] += v;
        __syncthreads();
    }
    int run = buf[t] - s;   // exclusive
    for (int j = 0; j < CH; ++j) {
        int idx = base + j;
        if (idx < NN) { rowptr[idx] = run; cursor[idx] = run; run += deg[idx]; }
    }
    if (t == 1023) rowptr[NN] = buf[1023];
}

__global__ __launch_bounds__(256) void scatter_kernel(const int* __restrict__ ei,
                                                      int* __restrict__ cursor,
                                                      int* __restrict__ csr_src) {
    int i = blockIdx.x * 256 + threadIdx.x;
    if (i >= ETOT) return;
    int s, d;
    if (i < NE) { s = ei[i]; d = ei[NE + i]; } else { s = i - NE; d = i - NE; }
    int pos = atomicAdd(&cursor[d], 1);
    csr_src[pos] = s;
}

// ---------------- bf16 MFMA GEMM: C8 = fp8(A * Bt^T) — fp8-only output ----------------
// 1D grid with XCD-locality swizzle: xcd c = id%8 owns A-panel stripe by = c+8q,
// iterating the 14 N-tiles in two halves of 7 (A-panel + B-half < 4 MB L2).
__global__ __launch_bounds__(256) void gemm_bf16(const __hip_bfloat16* __restrict__ A,
                                                 const __hip_bfloat16* __restrict__ Bt,
                                                 unsigned char* __restrict__ C8,
                                                 int M, int N, int K) {
    __shared__ __align__(16) unsigned short lsA[128 * 32];
    __shared__ __align__(16) unsigned short lsB[128 * 32];
    const int tid  = threadIdx.x;
    const int lane = tid & 63, wave = tid >> 6;
    const int wm = wave >> 1, wn = wave & 1;

    const int nbx = N >> 7;
    const int halfw = nbx >> 1;
    const int nby = (M + 127) >> 7;
    const int nq = (nby + 7) >> 3;
    const int c = blockIdx.x & 7;
    int j = blockIdx.x >> 3;
    const int half = j / (halfw * nq);
    j -= half * halfw * nq;
    const int q = j / halfw;
    const int k = j - q * halfw;
    const int by = c + 8 * q;
    const int bx = half * halfw + k;
    if (by >= nby) return;
    const int m0 = by * 128, n0 = bx * 128;

    floatx4 zero = {0.f, 0.f, 0.f, 0.f};
    floatx4 acc[4][4];
    #pragma unroll
    for (int i = 0; i < 4; ++i)
        #pragma unroll
        for (int jj = 0; jj < 4; ++jj) acc[i][jj] = zero;

    for (int k0 = 0; k0 < K; k0 += 32) {
        #pragma unroll
        for (int i = 0; i < 2; ++i) {
            int slot = tid + i * 256;
            int row = slot >> 2, seg = slot & 3;
            int gseg = seg ^ ((row >> 1) & 3);
            int gr = m0 + row; if (gr > M - 1) gr = M - 1;
            async_copy16(&lsA[slot * 8], A + (size_t)gr * K + k0 + gseg * 8);
        }
        #pragma unroll
        for (int i = 0; i < 2; ++i) {
            int slot = tid + i * 256;
            int row = slot >> 2, seg = slot & 3;
            int gseg = seg ^ ((row >> 1) & 3);
            async_copy16(&lsB[slot * 8], Bt + (size_t)(n0 + row) * K + k0 + gseg * 8);
        }
        __syncthreads();

        bf16x8 aF[4], bF[4];
        const int qq = lane >> 4;
        #pragma unroll
        for (int mt = 0; mt < 4; ++mt) {
            int row = wm * 64 + mt * 16 + (lane & 15);
            int seg = qq ^ ((row >> 1) & 3);
            aF[mt] = *(const bf16x8*)&lsA[row * 32 + seg * 8];
        }
        #pragma unroll
        for (int nt = 0; nt < 4; ++nt) {
            int row = wn * 64 + nt * 16 + (lane & 15);
            int seg = qq ^ ((row >> 1) & 3);
            bF[nt] = *(const bf16x8*)&lsB[row * 32 + seg * 8];
        }
        #pragma unroll
        for (int mt = 0; mt < 4; ++mt)
            #pragma unroll
            for (int nt = 0; nt < 4; ++nt)
                acc[mt][nt] = __builtin_amdgcn_mfma_f32_16x16x32_bf16(aF[mt], bF[nt], acc[mt][nt], 0, 0, 0);
        __syncthreads();
    }

    #pragma unroll
    for (int mt = 0; mt < 4; ++mt) {
        #pragma unroll
        for (int r = 0; r < 4; ++r) {
            int rowc = m0 + wm * 64 + mt * 16 + (lane >> 4) * 4 + r;
            if (rowc < M) {
                float v0 = acc[mt][0][r], v1 = acc[mt][1][r];
                float v2 = acc[mt][2][r], v3 = acc[mt][3][r];
                unsigned char q8[4];
#if __has_builtin(__builtin_amdgcn_cvt_pk_fp8_f32)
                u32 p01 = (u32)__builtin_amdgcn_cvt_pk_fp8_f32(v0, v1, 0, false);
                u32 p23 = (u32)__builtin_amdgcn_cvt_pk_fp8_f32(v2, v3, 0, false);
                q8[0] = p01 & 0xff; q8[1] = (p01 >> 8) & 0xff;
                q8[2] = p23 & 0xff; q8[3] = (p23 >> 8) & 0xff;
#else
                { __hip_fp8_e4m3 t0(v0), t1(v1), t2(v2), t3(v3);
                  q8[0] = t0.__x; q8[1] = t1.__x; q8[2] = t2.__x; q8[3] = t3.__x; }
#endif
                #pragma unroll
                for (int nt = 0; nt < 4; ++nt) {
                    int col = n0 + wn * 64 + nt * 16 + (lane & 15);
                    C8[(size_t)rowc * N + col] = q8[nt];
                }
            }
        }
    }
}

// ---------------- attention scores from fp8 h: as/ad[n,h] = sum_o h[n,h,o]*att[h,o] ----------------
__global__ __launch_bounds__(256) void attn_score(const unsigned char* __restrict__ h8,
                                                  const float* __restrict__ att_src,
                                                  const float* __restrict__ att_dst,
                                                  float* __restrict__ as_,
                                                  float* __restrict__ ad_) {
    int wave = threadIdx.x >> 6, lane = threadIdx.x & 63;
    int node = blockIdx.x * 4 + wave;
    if (node >= NN || lane >= NH) return;
    const uint2* hp = (const uint2*)(h8 + (size_t)node * DD1 + lane * OC);   // 32 B / head
    float s = 0.f, d = 0.f;
    #pragma unroll
    for (int jj = 0; jj < 4; ++jj) {
        uint2 u2 = hp[jj];
        u32 us[2] = {u2.x, u2.y};
        #pragma unroll
        for (int w = 0; w < 2; ++w) {
            #pragma unroll
            for (int b = 0; b < 4; ++b) {
                __hip_fp8_e4m3 t;
                t.__x = (us[w] >> (8 * b)) & 0xff;
                float v = (float)t;
                int o = jj * 8 + w * 4 + b;
                s += v * att_src[lane * OC + o];
                d += v * att_dst[lane * OC + o];
            }
        }
    }
    as_[(size_t)node * NH + lane] = s;
    ad_[(size_t)node * NH + lane] = d;
}

// ---------------- fused per-dst score + softmax -> bf16 alpha ----------------
// ONE gather pass (online max/den, SB-batched clamp-padded loads), logits parked
// in fp32 scratch, then a sequential normalize pass.
__global__ __launch_bounds__(256) void score_softmax(const int* __restrict__ rowptr,
                                                     const int* __restrict__ csr_src,
                                                     const float* __restrict__ as_,
                                                     const float* __restrict__ ad_,
                                                     float* __restrict__ sc32,
                                                     __hip_bfloat16* __restrict__ alpha) {
    int wave = threadIdx.x >> 6, lane = threadIdx.x & 63;
    int node = blockIdx.x * 4 + wave;
    if (node >= NN || lane >= NH) return;
    int e0 = rowptr[node], e1 = rowptr[node + 1];
    float adv = ad_[(size_t)node * NH + lane];

    float m = -1e30f, den = 0.f;
    for (int e = e0; e < e1; e += SB) {
        float v[SB];
        #pragma unroll
        for (int i = 0; i < SB; ++i) {
            int idx = (e + i < e1) ? e + i : e1 - 1;
            int s = csr_src[idx];
            v[i] = as_[(size_t)s * NH + lane];
        }
        #pragma unroll
        for (int i = 0; i < SB; ++i) {
            if (e + i < e1) {
                float vv = v[i] + adv;
                vv = vv > 0.f ? vv : 0.2f * vv;
                sc32[(size_t)(e + i) * NH + lane] = vv;
                if (vv > m) { den = den * __expf(m - vv) + 1.f; m = vv; }
                else den += __expf(vv - m);
            }
        }
    }
    float inv = 1.f / den;
    for (int e = e0; e < e1; ++e) {
        float vv = sc32[(size_t)e * NH + lane];
        alpha[(size_t)e * NH + lane] = __float2bfloat16(__expf(vv - m) * inv);
    }
}

// ---------------- node-boundary flush for the streaming aggregate ----------------
// LAYER==1: bf16 h1p[cur][slice] = BN1(ELU(acc + b1))
// LAYER==2: head-reduce in-wave, write per-slice partial (non-atomic) to h2part[cur][f][32]
template <int LAYER>
__device__ __forceinline__ void flush_node(float* acc, int cur, int f, int lane,
                                           const float* __restrict__ bias,
                                           const float* __restrict__ bng,
                                           const float* __restrict__ bnb,
                                           const float* __restrict__ bnm,
                                           const float* __restrict__ bnv,
                                           void* __restrict__ outp) {
    if constexpr (LAYER == 1) {
        int d0 = f * 256 + lane * 4;
        u32 r01, r23;
        {
            float v0 = acc[0] + bias[d0 + 0];
            float v1 = acc[1] + bias[d0 + 1];
            float v2 = acc[2] + bias[d0 + 2];
            float v3 = acc[3] + bias[d0 + 3];
            v0 = v0 > 0.f ? v0 : expm1f(v0);
            v1 = v1 > 0.f ? v1 : expm1f(v1);
            v2 = v2 > 0.f ? v2 : expm1f(v2);
            v3 = v3 > 0.f ? v3 : expm1f(v3);
            v0 = (v0 - bnm[d0 + 0]) * rsqrtf(bnv[d0 + 0] + EPS_BN) * bng[d0 + 0] + bnb[d0 + 0];
            v1 = (v1 - bnm[d0 + 1]) * rsqrtf(bnv[d0 + 1] + EPS_BN) * bng[d0 + 1] + bnb[d0 + 1];
            v2 = (v2 - bnm[d0 + 2]) * rsqrtf(bnv[d0 + 2] + EPS_BN) * bng[d0 + 2] + bnb[d0 + 2];
            v3 = (v3 - bnm[d0 + 3]) * rsqrtf(bnv[d0 + 3] + EPS_BN) * bng[d0 + 3] + bnb[d0 + 3];
            __hip_bfloat16 b0 = __float2bfloat16(v0), b1 = __float2bfloat16(v1);
            __hip_bfloat16 b2 = __float2bfloat16(v2), b3 = __float2bfloat16(v3);
            r01 = (u32)*(unsigned short*)&b0 | ((u32)*(unsigned short*)&b1 << 16);
            r23 = (u32)*(unsigned short*)&b2 | ((u32)*(unsigned short*)&b3 << 16);
        }
        uint2 pk; pk.x = r01; pk.y = r23;
        *(uint2*)((__hip_bfloat16*)outp + (size_t)cur * DD1 + d0) = pk;
    } else {
        // sum over the 8 heads held by this wave (lane groups stride 8)
        #pragma unroll
        for (int k = 0; k < 4; ++k) {
            acc[k] += __shfl_xor(acc[k], 8, 64);
            acc[k] += __shfl_xor(acc[k], 16, 64);
            acc[k] += __shfl_xor(acc[k], 32, 64);
        }
        if (lane < 8) {
            floatx4 pk;
            #pragma unroll
            for (int k = 0; k < 4; ++k) pk[k] = acc[k] * (1.f / NH);
            *(floatx4*)((float*)outp + ((size_t)cur * 7 + f) * OC + lane * 4) = pk;
        }
    }
    acc[0] = acc[1] = acc[2] = acc[3] = 0.f;
}

// ---------------- streaming slice-parallel aggregation ----------------
template <int LAYER>
__global__ __launch_bounds__(256) void attn_aggregate(const int* __restrict__ rowptr,
                                                      const int* __restrict__ csr_src,
                                                      const __hip_bfloat16* __restrict__ alpha,
                                                      const unsigned char* __restrict__ h8,
                                                      const float* __restrict__ bias,
                                                      const float* __restrict__ bng,
                                                      const float* __restrict__ bnb,
                                                      const float* __restrict__ bnm,
                                                      const float* __restrict__ bnv,
                                                      void* __restrict__ outp) {
    const int wv = threadIdx.x >> 6, lane = threadIdx.x & 63;
    const int w = blockIdx.x * 4 + wv;
    const int NWAVES = 7 * (NN / GRP);
    if (w >= NWAVES) return;
    const int f  = w % 7;             // feature slice (256 B of the 1792-B row)
    const int g  = w / 7;             // node group
    const int n0 = g * GRP;
    const int off  = f * 256 + lane * 4;
    const int head = f * 8 + (lane >> 3);

    const int e0 = rowptr[n0], e1 = rowptr[n0 + GRP];
    int cur = n0;
    int bound = rowptr[n0 + 1];

    float acc[4] = {0.f, 0.f, 0.f, 0.f};

    for (int e = e0; e < e1; e += EB) {
        u32   hv[EB];
        float av[EB];
        #pragma unroll
        for (int i = 0; i < EB; ++i) {
            int idx = (e + i < e1) ? e + i : e1 - 1;
            int s = csr_src[idx];
            hv[i] = *(const u32*)(h8 + (size_t)s * DD1 + off);
            float a = (float)alpha[(size_t)idx * NH + head];
            av[i] = (e + i < e1) ? a : 0.f;   // padded edges contribute 0
        }
        #pragma unroll
        for (int i = 0; i < EB; ++i) {
            if (e + i >= bound && e + i < e1) {   // crossed into next node
                flush_node<LAYER>(acc, cur, f, lane, bias, bng, bnb, bnm, bnv, outp);
                ++cur;
                bound = rowptr[cur + 1];
            }
            fma_fp8x4(hv[i], av[i], acc);
        }
    }
    flush_node<LAYER>(acc, cur, f, lane, bias, bng, bnb, bnm, bnv, outp);
}

// ---------------- mean pool: sum 7 slice-partials, atomic into graph sums ----------------
__global__ __launch_bounds__(256) void pool_kernel(const float* __restrict__ h2part,
                                                   const int* __restrict__ batch,
                                                   float* __restrict__ sums,
                                                   float* __restrict__ cnt) {
    int gid = blockIdx.x * 256 + threadIdx.x;
    if (gid >= NN * OC) return;
    int node = gid >> 5, ch = gid & 31;
    float v = 0.f;
    #pragma unroll
    for (int f = 0; f < 7; ++f) v += h2part[((size_t)node * 7 + f) * OC + ch];
    int g = batch[node];
    atomicAdd(&sums[g * OC + ch], v);
    if (ch == 0) atomicAdd(&cnt[g], 1.0f);
}

// final: pooled = sums/cnt; v = BN2(pooled + b2); out = v @ lin_w + lin_b
__global__ __launch_bounds__(128) void final_kernel(const float* __restrict__ sums,
                                                    const float* __restrict__ cnt,
                                                    const float* __restrict__ b2,
                                                    const float* __restrict__ bn2g,
                                                    const float* __restrict__ bn2b,
                                                    const float* __restrict__ bn2m,
                                                    const float* __restrict__ bn2v,
                                                    const float* __restrict__ lin_w,
                                                    const float* __restrict__ lin_b,
                                                    float* __restrict__ out) {
    int t = threadIdx.x;
    if (t >= NG * 2) return;
    int g = t >> 1, c = t & 1;
    float invc = 1.f / fmaxf(cnt[g], 1.f);
    float acc = lin_b[c];
    #pragma unroll
    for (int o = 0; o < OC; ++o) {
        float pooled = sums[g * OC + o] * invc + b2[o];
        float v = (pooled - bn2m[o]) * rsqrtf(bn2v[o] + EPS_BN) * bn2g[o] + bn2b[o];
        acc += v * lin_w[o * 2 + c];
    }
    out[t] = acc;
}

// ---------------- host-side launch ----------------
extern "C" void kernel_launch(void* const* d_in, const int* in_sizes, int n_in,
                              void* d_out, int out_size, void* d_ws, size_t ws_size,
                              hipStream_t stream) {
    const float* x    = (const float*)d_in[0];
    const int*   ei   = (const int*)d_in[1];
    const int*   bat  = (const int*)d_in[2];
    const float* W1   = (const float*)d_in[3];
    const float* at_s1 = (const float*)d_in[4];
    const float* at_d1 = (const float*)d_in[5];
    const float* b1   = (const float*)d_in[6];
    const float* bn1g = (const float*)d_in[7];
    const float* bn1b = (const float*)d_in[8];
    const float* bn1m = (const float*)d_in[9];
    const float* bn1v = (const float*)d_in[10];
    const float* W2   = (const float*)d_in[11];
    const float* at_s2 = (const float*)d_in[12];
    const float* at_d2 = (const float*)d_in[13];
    const float* b2   = (const float*)d_in[14];
    const float* bn2g = (const float*)d_in[15];
    const float* bn2b = (const float*)d_in[16];
    const float* bn2m = (const float*)d_in[17];
    const float* bn2v = (const float*)d_in[18];
    const float* linw = (const float*)d_in[19];
    const float* linb = (const float*)d_in[20];
    float* out = (float*)d_out;

    char* wsp = (char*)d_ws;
    auto alloc = [&](size_t bytes) -> void* {
        void* p = (void*)wsp;
        wsp += (bytes + 255) & ~(size_t)255;
        return p;
    };
    unsigned char*  h8  = (unsigned char*)alloc((size_t)NN * DD1);      // fp8 gemm output
    __hip_bfloat16* h1p = (__hip_bfloat16*)alloc((size_t)NN * DD1 * 2); // agg1 out (gemm2 A)
    __hip_bfloat16* xb  = (__hip_bfloat16*)alloc((size_t)NN * NF * 2);
    __hip_bfloat16* w1t = (__hip_bfloat16*)alloc((size_t)DD1 * NF * 2);
    __hip_bfloat16* w2t = (__hip_bfloat16*)alloc((size_t)DD1 * DD1 * 2);
    float* asb   = (float*)alloc((size_t)NN * NH * 4);
    float* adb   = (float*)alloc((size_t)NN * NH * 4);
    int*   deg   = (int*)alloc((size_t)NN * 4);
    int*   rowp  = (int*)alloc((size_t)(NN + 1) * 4);
    int*   curs  = (int*)alloc((size_t)NN * 4);
    int*   csr   = (int*)alloc((size_t)ETOT * 4);
    float* sc32  = (float*)alloc((size_t)ETOT * NH * 4);   // logit scratch
    __hip_bfloat16* alp = (__hip_bfloat16*)alloc((size_t)ETOT * NH * 2);
    float* h2part = (float*)alloc((size_t)NN * 7 * OC * 4);
    float* sums  = (float*)alloc((size_t)(NG * OC + NG) * 4);
    float* cnt   = sums + NG * OC;

    hipMemsetAsync(deg, 0, (size_t)NN * 4, stream);
    hipMemsetAsync(sums, 0, (size_t)(NG * OC + NG) * 4, stream);

    cast_bf16_kernel<<<(NN * NF + 255) / 256, 256, 0, stream>>>(x, xb, NN * NF);
    transpose_cast_kernel<<<dim3(DD1 / 32, NF / 32), 256, 0, stream>>>(W1, w1t, NF, DD1);
    transpose_cast_kernel<<<dim3(DD1 / 32, DD1 / 32), 256, 0, stream>>>(W2, w2t, DD1, DD1);
    hist_kernel<<<(ETOT + 255) / 256, 256, 0, stream>>>(ei, deg);
    scan_kernel<<<1, 1024, 0, stream>>>(deg, rowp, curs);
    scatter_kernel<<<(ETOT + 255) / 256, 256, 0, stream>>>(ei, curs, csr);

    const int AGG_BLOCKS = (7 * (NN / GRP) + 3) / 4;
    const int NBY = (NN + 127) / 128;                      // 157
    const int GEMM_BLOCKS = 8 * 2 * ((NBY + 7) / 8) * 7;   // 2240

    // layer 1
    gemm_bf16<<<GEMM_BLOCKS, 256, 0, stream>>>(xb, w1t, h8, NN, DD1, NF);
    attn_score<<<NN / 4, 256, 0, stream>>>(h8, at_s1, at_d1, asb, adb);
    score_softmax<<<NN / 4, 256, 0, stream>>>(rowp, csr, asb, adb, sc32, alp);
    attn_aggregate<1><<<AGG_BLOCKS, 256, 0, stream>>>(rowp, csr, alp, h8, b1, bn1g, bn1b, bn1m, bn1v, (void*)h1p);

    // layer 2
    gemm_bf16<<<GEMM_BLOCKS, 256, 0, stream>>>(h1p, w2t, h8, NN, DD1, DD1);
    attn_score<<<NN / 4, 256, 0, stream>>>(h8, at_s2, at_d2, asb, adb);
    score_softmax<<<NN / 4, 256, 0, stream>>>(rowp, csr, asb, adb, sc32, alp);
    attn_aggregate<2><<<AGG_BLOCKS, 256, 0, stream>>>(rowp, csr, alp, h8, b2, bn2g, bn2b, bn2m, bn2v, (void*)h2part);

    pool_kernel<<<(NN * OC) / 256, 256, 0, stream>>>(h2part, bat, sums, cnt);
    final_kernel<<<1, 128, 0, stream>>>(sums, cnt, b2, bn2g, bn2b, bn2m, bn2v, linw, linb, out);
}

// Round 9
// 748.379 us; speedup vs baseline: 1.4417x; 1.0145x over previous
//
#include <hip/hip_runtime.h>
#include <hip/hip_bf16.h>
#include <hip/hip_fp8.h>
#include <cstdint>
#include <cstddef>

// Problem constants
#define NN     20000     // nodes
#define NF     128       // in features
#define NH     56        // heads
#define OC     32        // out channels per head
#define DD1    1792      // NH*OC
#define NE     100000    // edges (before self loops)
#define ETOT   120000    // edges + self loops
#define NG     50        // graphs
#define EPS_BN 1e-5f
#define GRP    16        // nodes per wave in aggregate
#define EB     16        // edge batch (aggregate loads in flight)

typedef __bf16 bf16x8 __attribute__((ext_vector_type(8)));
typedef float  floatx4 __attribute__((ext_vector_type(4)));
typedef float  floatx2 __attribute__((ext_vector_type(2)));
typedef unsigned int u32;
typedef __attribute__((address_space(1))) u32 gu32;
typedef __attribute__((address_space(3))) u32 lu32;

__device__ __forceinline__ void async_copy16(void* lds, const void* g) {
    __builtin_amdgcn_global_load_lds((gu32*)const_cast<void*>(g), (lu32*)lds, 16, 0, 0);
}

// decode 4 fp8 (e4m3, packed in u32) to 4 floats (HW cvt when available)
__device__ __forceinline__ void dec_fp8x4(u32 u, float* v) {
#if __has_builtin(__builtin_amdgcn_cvt_pk_f32_fp8)
    floatx2 lo = __builtin_amdgcn_cvt_pk_f32_fp8(u, false);
    floatx2 hi = __builtin_amdgcn_cvt_pk_f32_fp8(u, true);
    v[0] = lo[0]; v[1] = lo[1]; v[2] = hi[0]; v[3] = hi[1];
#else
    #pragma unroll
    for (int b = 0; b < 4; ++b) {
        __hip_fp8_e4m3 t;
        t.__x = (u >> (8 * b)) & 0xff;
        v[b] = (float)t;
    }
#endif
}

__device__ __forceinline__ void fma_fp8x4(u32 u, float a, float* acc) {
    float v[4];
    dec_fp8x4(u, v);
    #pragma unroll
    for (int b = 0; b < 4; ++b) acc[b] += a * v[b];
}

// ---------------- elementwise cast fp32 -> bf16 ----------------
__global__ __launch_bounds__(256) void cast_bf16_kernel(const float* __restrict__ in,
                                                        __hip_bfloat16* __restrict__ out, int n) {
    int i = blockIdx.x * 256 + threadIdx.x;
    if (i < n) out[i] = __float2bfloat16(in[i]);
}

// ---------------- tiled transpose + cast: in[R][C] f32 -> out[C][R] bf16 ----------------
__global__ __launch_bounds__(256) void transpose_cast_kernel(const float* __restrict__ in,
                                                             __hip_bfloat16* __restrict__ out,
                                                             int R, int C) {
    __shared__ float tile[32][33];
    int c0 = blockIdx.x * 32, r0 = blockIdx.y * 32;
    int tx = threadIdx.x & 31, ty = threadIdx.x >> 5;   // ty in 0..7
    #pragma unroll
    for (int i = 0; i < 32; i += 8) {
        int r = r0 + ty + i, c = c0 + tx;
        if (r < R && c < C) tile[ty + i][tx] = in[(size_t)r * C + c];
    }
    __syncthreads();
    #pragma unroll
    for (int i = 0; i < 32; i += 8) {
        int c = c0 + ty + i, r = r0 + tx;
        if (c < C && r < R) out[(size_t)c * R + r] = __float2bfloat16(tile[tx][ty + i]);
    }
}

// ---------------- CSR build: histogram / scan / scatter ----------------
__global__ __launch_bounds__(256) void hist_kernel(const int* __restrict__ ei, int* __restrict__ deg) {
    int i = blockIdx.x * 256 + threadIdx.x;
    if (i >= ETOT) return;
    int dst = (i < NE) ? ei[NE + i] : (i - NE);
    atomicAdd(&deg[dst], 1);
}

__global__ __launch_bounds__(1024) void scan_kernel(const int* __restrict__ deg,
                                                    int* __restrict__ rowptr,
                                                    int* __restrict__ cursor) {
    __shared__ int buf[1024];
    int t = threadIdx.x;
    const int CH = (NN + 1023) >> 10;   // 20
    int base = t * CH;
    int s = 0;
    for (int j = 0; j < CH; ++j) { int idx = base + j; if (idx < NN) s += deg[idx]; }
    buf[t] = s;
    __syncthreads();
    for (int off = 1; off < 1024; off <<= 1) {
        int v = (t >= off) ? buf[t - off] : 0;
        __syncthreads();
        buf[t] += v;
        __syncthreads();
    }
    int run = buf[t] - s;   // exclusive
    for (int j = 0; j < CH; ++j) {
        int idx = base + j;
        if (idx < NN) { rowptr[idx] = run; cursor[idx] = run; run += deg[idx]; }
    }
    if (t == 1023) rowptr[NN] = buf[1023];
}

__global__ __launch_bounds__(256) void scatter_kernel(const int* __restrict__ ei,
                                                      int* __restrict__ cursor,
                                                      int* __restrict__ csr_src) {
    int i = blockIdx.x * 256 + threadIdx.x;
    if (i >= ETOT) return;
    int s, d;
    if (i < NE) { s = ei[i]; d = ei[NE + i]; } else { s = i - NE; d = i - NE; }
    int pos = atomicAdd(&cursor[d], 1);
    csr_src[pos] = s;
}

// ---------------- bf16 MFMA GEMM: C8 = fp8(A * Bt^T) — fp8-only output ----------------
// 1D grid with XCD-locality swizzle: xcd c = id%8 owns A-panel stripe by = c+8q,
// iterating the 14 N-tiles in two halves of 7 (A-panel + B-half < 4 MB L2).
__global__ __launch_bounds__(256) void gemm_bf16(const __hip_bfloat16* __restrict__ A,
                                                 const __hip_bfloat16* __restrict__ Bt,
                                                 unsigned char* __restrict__ C8,
                                                 int M, int N, int K) {
    __shared__ __align__(16) unsigned short lsA[128 * 32];
    __shared__ __align__(16) unsigned short lsB[128 * 32];
    const int tid  = threadIdx.x;
    const int lane = tid & 63, wave = tid >> 6;
    const int wm = wave >> 1, wn = wave & 1;

    const int nbx = N >> 7;
    const int halfw = nbx >> 1;
    const int nby = (M + 127) >> 7;
    const int nq = (nby + 7) >> 3;
    const int c = blockIdx.x & 7;
    int j = blockIdx.x >> 3;
    const int half = j / (halfw * nq);
    j -= half * halfw * nq;
    const int q = j / halfw;
    const int k = j - q * halfw;
    const int by = c + 8 * q;
    const int bx = half * halfw + k;
    if (by >= nby) return;
    const int m0 = by * 128, n0 = bx * 128;

    floatx4 zero = {0.f, 0.f, 0.f, 0.f};
    floatx4 acc[4][4];
    #pragma unroll
    for (int i = 0; i < 4; ++i)
        #pragma unroll
        for (int jj = 0; jj < 4; ++jj) acc[i][jj] = zero;

    for (int k0 = 0; k0 < K; k0 += 32) {
        #pragma unroll
        for (int i = 0; i < 2; ++i) {
            int slot = tid + i * 256;
            int row = slot >> 2, seg = slot & 3;
            int gseg = seg ^ ((row >> 1) & 3);
            int gr = m0 + row; if (gr > M - 1) gr = M - 1;
            async_copy16(&lsA[slot * 8], A + (size_t)gr * K + k0 + gseg * 8);
        }
        #pragma unroll
        for (int i = 0; i < 2; ++i) {
            int slot = tid + i * 256;
            int row = slot >> 2, seg = slot & 3;
            int gseg = seg ^ ((row >> 1) & 3);
            async_copy16(&lsB[slot * 8], Bt + (size_t)(n0 + row) * K + k0 + gseg * 8);
        }
        __syncthreads();

        bf16x8 aF[4], bF[4];
        const int qq = lane >> 4;
        #pragma unroll
        for (int mt = 0; mt < 4; ++mt) {
            int row = wm * 64 + mt * 16 + (lane & 15);
            int seg = qq ^ ((row >> 1) & 3);
            aF[mt] = *(const bf16x8*)&lsA[row * 32 + seg * 8];
        }
        #pragma unroll
        for (int nt = 0; nt < 4; ++nt) {
            int row = wn * 64 + nt * 16 + (lane & 15);
            int seg = qq ^ ((row >> 1) & 3);
            bF[nt] = *(const bf16x8*)&lsB[row * 32 + seg * 8];
        }
        #pragma unroll
        for (int mt = 0; mt < 4; ++mt)
            #pragma unroll
            for (int nt = 0; nt < 4; ++nt)
                acc[mt][nt] = __builtin_amdgcn_mfma_f32_16x16x32_bf16(aF[mt], bF[nt], acc[mt][nt], 0, 0, 0);
        __syncthreads();
    }

    #pragma unroll
    for (int mt = 0; mt < 4; ++mt) {
        #pragma unroll
        for (int r = 0; r < 4; ++r) {
            int rowc = m0 + wm * 64 + mt * 16 + (lane >> 4) * 4 + r;
            if (rowc < M) {
                float v0 = acc[mt][0][r], v1 = acc[mt][1][r];
                float v2 = acc[mt][2][r], v3 = acc[mt][3][r];
                unsigned char q8[4];
#if __has_builtin(__builtin_amdgcn_cvt_pk_fp8_f32)
                u32 p01 = (u32)__builtin_amdgcn_cvt_pk_fp8_f32(v0, v1, 0, false);
                u32 p23 = (u32)__builtin_amdgcn_cvt_pk_fp8_f32(v2, v3, 0, false);
                q8[0] = p01 & 0xff; q8[1] = (p01 >> 8) & 0xff;
                q8[2] = p23 & 0xff; q8[3] = (p23 >> 8) & 0xff;
#else
                { __hip_fp8_e4m3 t0(v0), t1(v1), t2(v2), t3(v3);
                  q8[0] = t0.__x; q8[1] = t1.__x; q8[2] = t2.__x; q8[3] = t3.__x; }
#endif
                #pragma unroll
                for (int nt = 0; nt < 4; ++nt) {
                    int col = n0 + wn * 64 + nt * 16 + (lane & 15);
                    C8[(size_t)rowc * N + col] = q8[nt];
                }
            }
        }
    }
}

// ---------------- attention scores from fp8 h: as/ad[n,h] = sum_o h[n,h,o]*att[h,o] ----------------
__global__ __launch_bounds__(256) void attn_score(const unsigned char* __restrict__ h8,
                                                  const float* __restrict__ att_src,
                                                  const float* __restrict__ att_dst,
                                                  float* __restrict__ as_,
                                                  float* __restrict__ ad_) {
    int wave = threadIdx.x >> 6, lane = threadIdx.x & 63;
    int node = blockIdx.x * 4 + wave;
    if (node >= NN || lane >= NH) return;
    const uint2* hp = (const uint2*)(h8 + (size_t)node * DD1 + lane * OC);   // 32 B / head
    float s = 0.f, d = 0.f;
    #pragma unroll
    for (int jj = 0; jj < 4; ++jj) {
        uint2 u2 = hp[jj];
        u32 us[2] = {u2.x, u2.y};
        #pragma unroll
        for (int w = 0; w < 2; ++w) {
            float v[4];
            dec_fp8x4(us[w], v);
            #pragma unroll
            for (int b = 0; b < 4; ++b) {
                int o = jj * 8 + w * 4 + b;
                s += v[b] * att_src[lane * OC + o];
                d += v[b] * att_dst[lane * OC + o];
            }
        }
    }
    as_[(size_t)node * NH + lane] = s;
    ad_[(size_t)node * NH + lane] = d;
}

// ---------------- node-boundary flush for the fused streaming aggregate ----------------
// acc holds UNNORMALIZED weighted sums; divide by den here.
// LAYER==1: bf16 h1p[cur][slice] = BN1(ELU(acc/den + b1))
// LAYER==2: head-reduce in-wave, write per-slice partial (non-atomic) to h2part[cur][f][32]
template <int LAYER>
__device__ __forceinline__ void flush_node(float* acc, float den, int cur, int f, int lane,
                                           const float* __restrict__ bias,
                                           const float* __restrict__ bng,
                                           const float* __restrict__ bnb,
                                           const float* __restrict__ bnm,
                                           const float* __restrict__ bnv,
                                           void* __restrict__ outp) {
    float inv = 1.f / den;
    #pragma unroll
    for (int k = 0; k < 4; ++k) acc[k] *= inv;

    if constexpr (LAYER == 1) {
        int d0 = f * 256 + lane * 4;
        u32 r01, r23;
        {
            float v0 = acc[0] + bias[d0 + 0];
            float v1 = acc[1] + bias[d0 + 1];
            float v2 = acc[2] + bias[d0 + 2];
            float v3 = acc[3] + bias[d0 + 3];
            v0 = v0 > 0.f ? v0 : expm1f(v0);
            v1 = v1 > 0.f ? v1 : expm1f(v1);
            v2 = v2 > 0.f ? v2 : expm1f(v2);
            v3 = v3 > 0.f ? v3 : expm1f(v3);
            v0 = (v0 - bnm[d0 + 0]) * rsqrtf(bnv[d0 + 0] + EPS_BN) * bng[d0 + 0] + bnb[d0 + 0];
            v1 = (v1 - bnm[d0 + 1]) * rsqrtf(bnv[d0 + 1] + EPS_BN) * bng[d0 + 1] + bnb[d0 + 1];
            v2 = (v2 - bnm[d0 + 2]) * rsqrtf(bnv[d0 + 2] + EPS_BN) * bng[d0 + 2] + bnb[d0 + 2];
            v3 = (v3 - bnm[d0 + 3]) * rsqrtf(bnv[d0 + 3] + EPS_BN) * bng[d0 + 3] + bnb[d0 + 3];
            __hip_bfloat16 b0 = __float2bfloat16(v0), b1 = __float2bfloat16(v1);
            __hip_bfloat16 b2 = __float2bfloat16(v2), b3 = __float2bfloat16(v3);
            r01 = (u32)*(unsigned short*)&b0 | ((u32)*(unsigned short*)&b1 << 16);
            r23 = (u32)*(unsigned short*)&b2 | ((u32)*(unsigned short*)&b3 << 16);
        }
        uint2 pk; pk.x = r01; pk.y = r23;
        *(uint2*)((__hip_bfloat16*)outp + (size_t)cur * DD1 + d0) = pk;
    } else {
        // sum over the 8 heads held by this wave (lane groups stride 8)
        #pragma unroll
        for (int k = 0; k < 4; ++k) {
            acc[k] += __shfl_xor(acc[k], 8, 64);
            acc[k] += __shfl_xor(acc[k], 16, 64);
            acc[k] += __shfl_xor(acc[k], 32, 64);
        }
        if (lane < 8) {
            floatx4 pk;
            #pragma unroll
            for (int k = 0; k < 4; ++k) pk[k] = acc[k] * (1.f / NH);
            *(floatx4*)((float*)outp + ((size_t)cur * 7 + f) * OC + lane * 4) = pk;
        }
    }
    acc[0] = acc[1] = acc[2] = acc[3] = 0.f;
}

// ---------------- fused streaming aggregation with ONLINE SOFTMAX ----------------
// wave = (slice f in [0,7), node group of GRP nodes). Lane covers 4 fp8 features
// at byte offset f*256 + lane*4, head = f*8 + (lane>>3). Per edge: gather h row
// u32 + as[src][head]; online max/den rescale; flush (divide by den) at bounds.
template <int LAYER>
__global__ __launch_bounds__(256) void attn_aggregate(const int* __restrict__ rowptr,
                                                      const int* __restrict__ csr_src,
                                                      const float* __restrict__ as_,
                                                      const float* __restrict__ ad_,
                                                      const unsigned char* __restrict__ h8,
                                                      const float* __restrict__ bias,
                                                      const float* __restrict__ bng,
                                                      const float* __restrict__ bnb,
                                                      const float* __restrict__ bnm,
                                                      const float* __restrict__ bnv,
                                                      void* __restrict__ outp) {
    const int wv = threadIdx.x >> 6, lane = threadIdx.x & 63;
    const int w = blockIdx.x * 4 + wv;
    const int NWAVES = 7 * (NN / GRP);
    if (w >= NWAVES) return;
    const int f  = w % 7;             // feature slice (256 B of the 1792-B row)
    const int g  = w / 7;             // node group
    const int n0 = g * GRP;
    const int off  = f * 256 + lane * 4;
    const int head = f * 8 + (lane >> 3);

    const int e0 = rowptr[n0], e1 = rowptr[n0 + GRP];
    int cur = n0;
    int bound = rowptr[n0 + 1];
    float adv = ad_[(size_t)cur * NH + head];

    float acc[4] = {0.f, 0.f, 0.f, 0.f};
    float m = -1e30f, den = 0.f;

    for (int e = e0; e < e1; e += EB) {
        u32   hv[EB];
        float sv[EB];
        // unconditional clamp-padded loads: EB independent chains in flight
        #pragma unroll
        for (int i = 0; i < EB; ++i) {
            int idx = (e + i < e1) ? e + i : e1 - 1;
            int s = csr_src[idx];
            hv[i] = *(const u32*)(h8 + (size_t)s * DD1 + off);
            sv[i] = as_[(size_t)s * NH + head];
        }
        #pragma unroll
        for (int i = 0; i < EB; ++i) {
            if (e + i >= e1) break;                 // tail padding: skip
            if (e + i >= bound) {                   // crossed into next node
                flush_node<LAYER>(acc, den, cur, f, lane, bias, bng, bnb, bnm, bnv, outp);
                ++cur;
                bound = rowptr[cur + 1];
                adv = ad_[(size_t)cur * NH + head];
                m = -1e30f; den = 0.f;
            }
            float lr = sv[i] + adv;
            lr = lr > 0.f ? lr : 0.2f * lr;         // leaky_relu
            float wgt;
            if (lr > m) {                           // new max: rescale history
                float scale = __expf(m - lr);
                den = den * scale + 1.f;
                #pragma unroll
                for (int k = 0; k < 4; ++k) acc[k] *= scale;
                m = lr;
                wgt = 1.f;
            } else {
                wgt = __expf(lr - m);
                den += wgt;
            }
            fma_fp8x4(hv[i], wgt, acc);
        }
    }
    flush_node<LAYER>(acc, den, cur, f, lane, bias, bng, bnb, bnm, bnv, outp);
}

// ---------------- mean pool: sum 7 slice-partials, atomic into graph sums ----------------
__global__ __launch_bounds__(256) void pool_kernel(const float* __restrict__ h2part,
                                                   const int* __restrict__ batch,
                                                   float* __restrict__ sums,
                                                   float* __restrict__ cnt) {
    int gid = blockIdx.x * 256 + threadIdx.x;
    if (gid >= NN * OC) return;
    int node = gid >> 5, ch = gid & 31;
    float v = 0.f;
    #pragma unroll
    for (int f = 0; f < 7; ++f) v += h2part[((size_t)node * 7 + f) * OC + ch];
    int g = batch[node];
    atomicAdd(&sums[g * OC + ch], v);
    if (ch == 0) atomicAdd(&cnt[g], 1.0f);
}

// final: pooled = sums/cnt; v = BN2(pooled + b2); out = v @ lin_w + lin_b
__global__ __launch_bounds__(128) void final_kernel(const float* __restrict__ sums,
                                                    const float* __restrict__ cnt,
                                                    const float* __restrict__ b2,
                                                    const float* __restrict__ bn2g,
                                                    const float* __restrict__ bn2b,
                                                    const float* __restrict__ bn2m,
                                                    const float* __restrict__ bn2v,
                                                    const float* __restrict__ lin_w,
                                                    const float* __restrict__ lin_b,
                                                    float* __restrict__ out) {
    int t = threadIdx.x;
    if (t >= NG * 2) return;
    int g = t >> 1, c = t & 1;
    float invc = 1.f / fmaxf(cnt[g], 1.f);
    float acc = lin_b[c];
    #pragma unroll
    for (int o = 0; o < OC; ++o) {
        float pooled = sums[g * OC + o] * invc + b2[o];
        float v = (pooled - bn2m[o]) * rsqrtf(bn2v[o] + EPS_BN) * bn2g[o] + bn2b[o];
        acc += v * lin_w[o * 2 + c];
    }
    out[t] = acc;
}

// ---------------- host-side launch ----------------
extern "C" void kernel_launch(void* const* d_in, const int* in_sizes, int n_in,
                              void* d_out, int out_size, void* d_ws, size_t ws_size,
                              hipStream_t stream) {
    const float* x    = (const float*)d_in[0];
    const int*   ei   = (const int*)d_in[1];
    const int*   bat  = (const int*)d_in[2];
    const float* W1   = (const float*)d_in[3];
    const float* at_s1 = (const float*)d_in[4];
    const float* at_d1 = (const float*)d_in[5];
    const float* b1   = (const float*)d_in[6];
    const float* bn1g = (const float*)d_in[7];
    const float* bn1b = (const float*)d_in[8];
    const float* bn1m = (const float*)d_in[9];
    const float* bn1v = (const float*)d_in[10];
    const float* W2   = (const float*)d_in[11];
    const float* at_s2 = (const float*)d_in[12];
    const float* at_d2 = (const float*)d_in[13];
    const float* b2   = (const float*)d_in[14];
    const float* bn2g = (const float*)d_in[15];
    const float* bn2b = (const float*)d_in[16];
    const float* bn2m = (const float*)d_in[17];
    const float* bn2v = (const float*)d_in[18];
    const float* linw = (const float*)d_in[19];
    const float* linb = (const float*)d_in[20];
    float* out = (float*)d_out;

    char* wsp = (char*)d_ws;
    auto alloc = [&](size_t bytes) -> void* {
        void* p = (void*)wsp;
        wsp += (bytes + 255) & ~(size_t)255;
        return p;
    };
    unsigned char*  h8  = (unsigned char*)alloc((size_t)NN * DD1);      // fp8 gemm output
    __hip_bfloat16* h1p = (__hip_bfloat16*)alloc((size_t)NN * DD1 * 2); // agg1 out (gemm2 A)
    __hip_bfloat16* xb  = (__hip_bfloat16*)alloc((size_t)NN * NF * 2);
    __hip_bfloat16* w1t = (__hip_bfloat16*)alloc((size_t)DD1 * NF * 2);
    __hip_bfloat16* w2t = (__hip_bfloat16*)alloc((size_t)DD1 * DD1 * 2);
    float* asb   = (float*)alloc((size_t)NN * NH * 4);
    float* adb   = (float*)alloc((size_t)NN * NH * 4);
    int*   deg   = (int*)alloc((size_t)NN * 4);
    int*   rowp  = (int*)alloc((size_t)(NN + 1) * 4);
    int*   curs  = (int*)alloc((size_t)NN * 4);
    int*   csr   = (int*)alloc((size_t)ETOT * 4);
    float* h2part = (float*)alloc((size_t)NN * 7 * OC * 4);
    float* sums  = (float*)alloc((size_t)(NG * OC + NG) * 4);
    float* cnt   = sums + NG * OC;

    hipMemsetAsync(deg, 0, (size_t)NN * 4, stream);
    hipMemsetAsync(sums, 0, (size_t)(NG * OC + NG) * 4, stream);

    cast_bf16_kernel<<<(NN * NF + 255) / 256, 256, 0, stream>>>(x, xb, NN * NF);
    transpose_cast_kernel<<<dim3(DD1 / 32, NF / 32), 256, 0, stream>>>(W1, w1t, NF, DD1);
    transpose_cast_kernel<<<dim3(DD1 / 32, DD1 / 32), 256, 0, stream>>>(W2, w2t, DD1, DD1);
    hist_kernel<<<(ETOT + 255) / 256, 256, 0, stream>>>(ei, deg);
    scan_kernel<<<1, 1024, 0, stream>>>(deg, rowp, curs);
    scatter_kernel<<<(ETOT + 255) / 256, 256, 0, stream>>>(ei, curs, csr);

    const int AGG_BLOCKS = (7 * (NN / GRP) + 3) / 4;
    const int NBY = (NN + 127) / 128;                      // 157
    const int GEMM_BLOCKS = 8 * 2 * ((NBY + 7) / 8) * 7;   // 2240

    // layer 1
    gemm_bf16<<<GEMM_BLOCKS, 256, 0, stream>>>(xb, w1t, h8, NN, DD1, NF);
    attn_score<<<NN / 4, 256, 0, stream>>>(h8, at_s1, at_d1, asb, adb);
    attn_aggregate<1><<<AGG_BLOCKS, 256, 0, stream>>>(rowp, csr, asb, adb, h8, b1, bn1g, bn1b, bn1m, bn1v, (void*)h1p);

    // layer 2
    gemm_bf16<<<GEMM_BLOCKS, 256, 0, stream>>>(h1p, w2t, h8, NN, DD1, DD1);
    attn_score<<<NN / 4, 256, 0, stream>>>(h8, at_s2, at_d2, asb, adb);
    attn_aggregate<2><<<AGG_BLOCKS, 256, 0, stream>>>(rowp, csr, asb, adb, h8, b2, bn2g, bn2b, bn2m, bn2v, (void*)h2part);

    pool_kernel<<<(NN * OC) / 256, 256, 0, stream>>>(h2part, bat, sums, cnt);
    final_kernel<<<1, 128, 0, stream>>>(sums, cnt, b2, bn2g, bn2b, bn2m, bn2v, linw, linb, out);
}